// Round 1
// 1151.515 us; speedup vs baseline: 1.0806x; 1.0806x over previous
//
#include <hip/hip_runtime.h>
#include <hip/hip_bf16.h>
#include <math.h>

// Problem constants
#define BB 256
#define LL 16
#define HH 256
#define VV 5000
#define NPG 150
#define DEG 4
#define NSTEPS 4
#define OUTD 2000
#define NN (BB*NPG)      // 38400
#define EE (BB*NPG*DEG)  // 153600
#define BL (BB*LL)       // 4096
#define VPAD 5120        // logits column pad (40*128)
#define KPAD 5024        // Pm K pad (157*32)

// ---------------- helpers ----------------
__device__ __forceinline__ float wred_sum(float v){
  #pragma unroll
  for(int o=32;o;o>>=1) v += __shfl_down(v,o,64);
  return v;
}
__device__ __forceinline__ float wred_max(float v){
  #pragma unroll
  for(int o=32;o;o>>=1) v = fmaxf(v,__shfl_down(v,o,64));
  return v;
}
__device__ __forceinline__ float block_sum256(float v, float* sh){
  v = wred_sum(v);
  __syncthreads();
  if((threadIdx.x&63)==0) sh[threadIdx.x>>6]=v;
  __syncthreads();
  return sh[0]+sh[1]+sh[2]+sh[3];
}
__device__ __forceinline__ float block_max256(float v, float* sh){
  v = wred_max(v);
  __syncthreads();
  if((threadIdx.x&63)==0) sh[threadIdx.x>>6]=v;
  __syncthreads();
  return fmaxf(fmaxf(sh[0],sh[1]),fmaxf(sh[2],sh[3]));
}
__device__ __forceinline__ float eluf(float x){ return x>0.f ? x : expm1f(x); }
__device__ __forceinline__ float sigf(float x){ return 1.f/(1.f+expf(-x)); }
__device__ __forceinline__ float b2f(unsigned short s){
  union{float f; unsigned int u;} x; x.u = ((unsigned int)s)<<16; return x.f;
}
__device__ __forceinline__ unsigned short f2bf_bits(float x){
  union { __hip_bfloat16 h; unsigned short s; } u; u.h = __float2bfloat16(x); return u.s;
}

// async global->LDS 16B (gfx950), lds dest = wave-uniform base + lane*16
__device__ __forceinline__ void async16(void* lds, const void* g){
  __builtin_amdgcn_global_load_lds(
      (const __attribute__((address_space(1))) unsigned int*)g,
      (__attribute__((address_space(3))) unsigned int*)lds, 16, 0, 0);
}

typedef __attribute__((ext_vector_type(8))) short short8;
typedef __attribute__((ext_vector_type(4))) float f32x4;

__device__ __forceinline__ short8 pack8(float4 a, float4 b){
  short8 r;
  r[0]=(short)f2bf_bits(a.x); r[1]=(short)f2bf_bits(a.y);
  r[2]=(short)f2bf_bits(a.z); r[3]=(short)f2bf_bits(a.w);
  r[4]=(short)f2bf_bits(b.x); r[5]=(short)f2bf_bits(b.y);
  r[6]=(short)f2bf_bits(b.z); r[7]=(short)f2bf_bits(b.w);
  return r;
}

// =======================================================================
// MFMA GEMM, C[m,n] = sum_k A[m,k]*Bt[n,k].  128x128 tile, BK=32, 4 waves.
// EPI: 0 = f32 store (+bias, col<Nreal), 1 = bf16 store, 2 = f32 atomicAdd
//      (EPI 2: optional per-row scale rscale[row])
// =======================================================================
template<int EPI>
__global__ __launch_bounds__(256) void mfma_bt_bf16_k(
    const __hip_bfloat16* __restrict__ A, const __hip_bfloat16* __restrict__ Bt,
    float* __restrict__ Cf, __hip_bfloat16* __restrict__ Cb,
    int lda, int ldb, int ldc, int Nreal,
    int kItersTotal, int kPerSplit, const float* __restrict__ bias,
    const float* __restrict__ rscale)
{
  __shared__ __hip_bfloat16 As[128*32];
  __shared__ __hip_bfloat16 Bs[128*32];
  const int bm = blockIdx.y*128, bn = blockIdx.x*128;
  const int tid = threadIdx.x;
  int k0 = blockIdx.z * kPerSplit;
  int k1 = k0 + kPerSplit; if (k1 > kItersTotal) k1 = kItersTotal;
  const int lane = tid & 63, wave = tid >> 6;
  const int quad = lane >> 4, r16 = lane & 15;
  const int wr = wave >> 1, wc = wave & 1;
  f32x4 acc[4][4] = {};
  const int c0 = tid, c1 = tid + 256;
  const int ar0 = c0 >> 2, ak0 = (c0 & 3)*8;
  const int ar1 = c1 >> 2, ak1 = (c1 & 3)*8;
  const __hip_bfloat16* Ab = A + (size_t)bm*lda;
  const __hip_bfloat16* Bb = Bt + (size_t)bn*ldb;
  for (int kk = k0; kk < k1; ++kk){
    const int kb = kk*32;
    async16(&As[c0*8], Ab + (size_t)ar0*lda + kb + ak0);
    async16(&As[c1*8], Ab + (size_t)ar1*lda + kb + ak1);
    async16(&Bs[c0*8], Bb + (size_t)ar0*ldb + kb + ak0);
    async16(&Bs[c1*8], Bb + (size_t)ar1*ldb + kb + ak1);
    __syncthreads();
    short8 av[4], bv[4];
    #pragma unroll
    for (int i=0;i<4;i++){
      av[i] = *(const short8*)&As[(wr*64 + i*16 + r16)*32 + quad*8];
      bv[i] = *(const short8*)&Bs[(wc*64 + i*16 + r16)*32 + quad*8];
    }
    #pragma unroll
    for (int i=0;i<4;i++)
      #pragma unroll
      for (int j=0;j<4;j++)
        acc[i][j] = __builtin_amdgcn_mfma_f32_16x16x32_bf16(av[i], bv[j], acc[i][j], 0,0,0);
    __syncthreads();
  }
  #pragma unroll
  for (int i=0;i<4;i++){
    int row = bm + wr*64 + i*16 + quad*4;
    #pragma unroll
    for (int j=0;j<4;j++){
      int col = bn + wc*64 + j*16 + r16;
      if (col >= Nreal) continue;
      #pragma unroll
      for (int r=0;r<4;r++){
        float v = acc[i][j][r];
        if (EPI==0){ if (bias) v += bias[col]; Cf[(size_t)(row+r)*ldc + col] = v; }
        else if (EPI==1){ Cb[(size_t)(row+r)*ldc + col] = __float2bfloat16(v); }
        else { if (rscale) v *= rscale[row+r]; atomicAdd(&Cf[(size_t)(row+r)*ldc + col], v); }
      }
    }
  }
}

// Same GEMM, f32 global operands, packed bf16 staging (2x float4 -> 1x b128 LDS write)
template<int EPI>
__global__ __launch_bounds__(256) void mfma_bt_f32_k(
    const float* __restrict__ A, const float* __restrict__ Bt,
    float* __restrict__ Cf, __hip_bfloat16* __restrict__ Cb,
    int lda, int ldb, int ldc, int Nreal,
    int kIters, const float* __restrict__ bias)
{
  __shared__ __hip_bfloat16 As[128*32];
  __shared__ __hip_bfloat16 Bs[128*32];
  const int bm = blockIdx.y*128, bn = blockIdx.x*128;
  const int tid = threadIdx.x;
  const int lane = tid & 63, wave = tid >> 6;
  const int quad = lane >> 4, r16 = lane & 15;
  const int wr = wave >> 1, wc = wave & 1;
  f32x4 acc[4][4] = {};
  for (int kk = 0; kk < kIters; ++kk){
    const int kb = kk*32;
    #pragma unroll
    for (int i=0;i<2;i++){
      int c = tid + i*256;
      int row = c >> 2, k0 = (c & 3)*8;
      const float* src = A + (size_t)(bm+row)*lda + kb + k0;
      float4 v0 = *(const float4*)(src);
      float4 v1 = *(const float4*)(src+4);
      *(short8*)&As[row*32 + k0] = pack8(v0, v1);
    }
    #pragma unroll
    for (int i=0;i<2;i++){
      int c = tid + i*256;
      int row = c >> 2, k0 = (c & 3)*8;
      float4 v0 = {0.f,0.f,0.f,0.f}, v1 = {0.f,0.f,0.f,0.f};
      if (bn + row < Nreal){
        const float* src = Bt + (size_t)(bn+row)*ldb + kb + k0;
        v0 = *(const float4*)(src);
        v1 = *(const float4*)(src+4);
      }
      *(short8*)&Bs[row*32 + k0] = pack8(v0, v1);
    }
    __syncthreads();
    short8 av[4], bv[4];
    #pragma unroll
    for (int i=0;i<4;i++){
      av[i] = *(const short8*)&As[(wr*64 + i*16 + r16)*32 + quad*8];
      bv[i] = *(const short8*)&Bs[(wc*64 + i*16 + r16)*32 + quad*8];
    }
    #pragma unroll
    for (int i=0;i<4;i++)
      #pragma unroll
      for (int j=0;j<4;j++)
        acc[i][j] = __builtin_amdgcn_mfma_f32_16x16x32_bf16(av[i], bv[j], acc[i][j], 0,0,0);
    __syncthreads();
  }
  #pragma unroll
  for (int i=0;i<4;i++){
    int row = bm + wr*64 + i*16 + quad*4;
    #pragma unroll
    for (int j=0;j<4;j++){
      int col = bn + wc*64 + j*16 + r16;
      if (col >= Nreal) continue;
      #pragma unroll
      for (int r=0;r<4;r++){
        float v = acc[i][j][r];
        if (EPI==0){ if (bias) v += bias[col]; Cf[(size_t)(row+r)*ldc + col] = v; }
        else { Cb[(size_t)(row+r)*ldc + col] = __float2bfloat16(v); }
      }
    }
  }
}

// Fused logits GEMM + exp epilogue: Pm[r][c] = exp(logit) (unnormalized, bf16),
// row_sum[r] += partial sums (cols 0..VV), e_def[r] = exp(logit[VV]).
__global__ __launch_bounds__(256) void gemm_exp_k(
    const __hip_bfloat16* __restrict__ A, const __hip_bfloat16* __restrict__ Bt,
    __hip_bfloat16* __restrict__ Pm, float* __restrict__ row_sum,
    float* __restrict__ e_def)
{
  __shared__ __hip_bfloat16 As[128*32];
  __shared__ __hip_bfloat16 Bs[128*32];
  const int bm = blockIdx.y*128, bn = blockIdx.x*128;
  const int tid = threadIdx.x;
  const int lane = tid & 63, wave = tid >> 6;
  const int quad = lane >> 4, r16 = lane & 15;
  const int wr = wave >> 1, wc = wave & 1;
  f32x4 acc[4][4] = {};
  const int c0 = tid, c1 = tid + 256;
  const int ar0 = c0 >> 2, ak0 = (c0 & 3)*8;
  const int ar1 = c1 >> 2, ak1 = (c1 & 3)*8;
  const __hip_bfloat16* Ab = A + (size_t)bm*HH;
  const __hip_bfloat16* Bb = Bt + (size_t)bn*HH;
  for (int kk = 0; kk < HH/32; ++kk){
    const int kb = kk*32;
    async16(&As[c0*8], Ab + (size_t)ar0*HH + kb + ak0);
    async16(&As[c1*8], Ab + (size_t)ar1*HH + kb + ak1);
    async16(&Bs[c0*8], Bb + (size_t)ar0*HH + kb + ak0);
    async16(&Bs[c1*8], Bb + (size_t)ar1*HH + kb + ak1);
    __syncthreads();
    short8 av[4], bv[4];
    #pragma unroll
    for (int i=0;i<4;i++){
      av[i] = *(const short8*)&As[(wr*64 + i*16 + r16)*32 + quad*8];
      bv[i] = *(const short8*)&Bs[(wc*64 + i*16 + r16)*32 + quad*8];
    }
    #pragma unroll
    for (int i=0;i<4;i++)
      #pragma unroll
      for (int j=0;j<4;j++)
        acc[i][j] = __builtin_amdgcn_mfma_f32_16x16x32_bf16(av[i], bv[j], acc[i][j], 0,0,0);
    __syncthreads();
  }
  #pragma unroll
  for (int i=0;i<4;i++){
    int rowb = bm + wr*64 + i*16 + quad*4;
    float rsum[4] = {0.f,0.f,0.f,0.f};
    #pragma unroll
    for (int j=0;j<4;j++){
      int col = bn + wc*64 + j*16 + r16;
      #pragma unroll
      for (int r=0;r<4;r++){
        float e = (col <= VV) ? expf(acc[i][j][r]) : 0.f;
        rsum[r] += e;
        if (col < KPAD) Pm[(size_t)(rowb+r)*KPAD + col] = __float2bfloat16(col < VV ? e : 0.f);
        if (col == VV) e_def[rowb+r] = e;
      }
    }
    #pragma unroll
    for (int r=0;r<4;r++){
      float s = rsum[r];
      s += __shfl_xor(s, 1, 64);
      s += __shfl_xor(s, 2, 64);
      s += __shfl_xor(s, 4, 64);
      s += __shfl_xor(s, 8, 64);
      if (r16 == 0) atomicAdd(&row_sum[rowb+r], s);
    }
  }
}

// =======================================================================
// Persistent batch-parallel LSTM, v2: 16 blocks x 1024 threads (16 waves).
// Wave w owns hidden units [16w,16w+16) for ALL FOUR gates -> c/h update is
// per-lane register math (no Gbuf/cst/hst LDS staging, 1 barrier/step).
// Gate rows 0..63 (waves 0..3) of Whh cached in LDS (132KB); waves 4..15
// stream their 32KB/step slice from L2 (weights stay L2-resident).
// acc[g][r] holds C[batch=quad*4+r][hh=hb+r16] for gate g.
// =======================================================================
__global__ __launch_bounds__(1024) void lstm_persist_k(
    const float* __restrict__ gX, const __hip_bfloat16* __restrict__ Whh_bf,
    const int* __restrict__ lengths,
    float* __restrict__ h_out, __hip_bfloat16* __restrict__ hbf_out)
{
  __shared__ __hip_bfloat16 Wl[256*264];      // [g*64+rr][c], rr<64: 132KB
  __shared__ __hip_bfloat16 hbuf[2][16*264];  // double-buffered recurrent h (bf16)
  __shared__ int len_s[16];
  const int bg = blockIdx.x, tid = threadIdx.x;
  const int lane = tid & 63, w = tid >> 6;
  const int quad = lane >> 4, r16 = lane & 15;
  const int hb = w*16;
  // preload LDS weight slab: Wl[(g*64+rr)*264+c] = Whh[g*256+rr][c], rr<64
  for (int c = tid; c < 8192; c += 1024){
    int row = c >> 5, ci = (c & 31)*8;
    int g = row >> 6, rr = row & 63;
    *(short8*)&Wl[row*264 + ci] = *(const short8*)&Whh_bf[((size_t)(g*256+rr))*256 + ci];
  }
  for (int i = tid; i < 16*264; i += 1024) hbuf[0][i] = __float2bfloat16(0.f);
  if (tid < 16) len_s[tid] = lengths[bg*16 + tid];
  __syncthreads();
  int lenr[4];
  #pragma unroll
  for (int r=0;r<4;r++) lenr[r] = len_s[quad*4 + r];
  f32x4 cstate = {0.f,0.f,0.f,0.f};
  f32x4 hstate = {0.f,0.f,0.f,0.f};
  int p = 0;
  for (int t=0; t<LL; t++){
    f32x4 acc[4] = {};
    const __hip_bfloat16* hr = hbuf[p];
    if (w < 4){
      #pragma unroll
      for (int kc=0; kc<8; kc++){
        short8 a = *(const short8*)&hr[r16*264 + kc*32 + quad*8];
        #pragma unroll
        for (int g=0; g<4; g++){
          short8 b = *(const short8*)&Wl[(g*64 + hb + r16)*264 + kc*32 + quad*8];
          acc[g] = __builtin_amdgcn_mfma_f32_16x16x32_bf16(a, b, acc[g], 0,0,0);
        }
      }
    } else {
      #pragma unroll
      for (int kc=0; kc<8; kc++){
        short8 a = *(const short8*)&hr[r16*264 + kc*32 + quad*8];
        #pragma unroll
        for (int g=0; g<4; g++){
          short8 b = *(const short8*)&Whh_bf[((size_t)(g*256 + hb + r16))*256 + kc*32 + quad*8];
          acc[g] = __builtin_amdgcn_mfma_f32_16x16x32_bf16(a, b, acc[g], 0,0,0);
        }
      }
    }
    #pragma unroll
    for (int r=0;r<4;r++){
      int batch = quad*4 + r;
      const float* gx = gX + ((size_t)((bg*16+batch)*LL + t))*(4*HH) + hb + r16;
      float gi = acc[0][r] + gx[0];
      float gf = acc[1][r] + gx[HH];
      float gc = acc[2][r] + gx[2*HH];
      float go = acc[3][r] + gx[3*HH];
      float cn = sigf(gf)*cstate[r] + sigf(gi)*tanhf(gc);
      float hn = sigf(go)*tanhf(cn);
      if (t < lenr[r]){ cstate[r] = cn; hstate[r] = hn; }
      hbuf[p^1][batch*264 + hb + r16] = __float2bfloat16(hstate[r]);
    }
    p ^= 1;
    __syncthreads();
  }
  #pragma unroll
  for (int r=0;r<4;r++){
    int batch = quad*4 + r;
    size_t o = (size_t)(bg*16+batch)*HH + hb + r16;
    h_out[o] = hstate[r];
    hbf_out[o] = __float2bfloat16(hstate[r]);
  }
}

// Persistent batch-parallel decoder RNN v2: 16 blocks x 1024 threads.
// Entire Whh (128KB) cached in LDS; qp and x-state in registers; step 0 has
// h=0 so its MFMA is skipped entirely.
__global__ __launch_bounds__(1024) void dec_persist_k(
    const __hip_bfloat16* __restrict__ Qbf, const __hip_bfloat16* __restrict__ Wih_bf,
    const __hip_bfloat16* __restrict__ Whh_bf,
    const float* __restrict__ bih, const float* __restrict__ bhh,
    float* __restrict__ Hins)
{
  __shared__ __hip_bfloat16 Wl[256*264];     // full Whh, 132KB
  __shared__ __hip_bfloat16 xb[2][16*264];
  const int bg = blockIdx.x, tid = threadIdx.x;
  const int lane = tid & 63, w = tid >> 6;
  const int quad = lane >> 4, r16 = lane & 15;
  const int col = w*16 + r16;
  for (int c = tid; c < 8192; c += 1024){
    int row = c >> 5, ci = (c & 31)*8;
    *(short8*)&Wl[row*264 + ci] = *(const short8*)&Whh_bf[(size_t)row*256 + ci];
  }
  // qp = Q @ Wih^T  (A rows straight from global; Wih streamed from L2 once)
  f32x4 qp = {};
  #pragma unroll
  for (int kc=0; kc<8; kc++){
    short8 a = *(const short8*)&Qbf[(size_t)(bg*16 + r16)*HH + kc*32 + quad*8];
    short8 b = *(const short8*)&Wih_bf[(size_t)col*HH + kc*32 + quad*8];
    qp = __builtin_amdgcn_mfma_f32_16x16x32_bf16(a, b, qp, 0,0,0);
  }
  const float bihv = bih[col], bhhv = bhh[col];
  __syncthreads();           // Wl ready
  // s = 0: hx=0 -> x = relu(qp + bih + bhh)
  #pragma unroll
  for (int r=0;r<4;r++){
    int batch = quad*4 + r;
    float v = fmaxf(qp[r] + bihv + bhhv, 0.f);
    xb[0][batch*264 + col] = __float2bfloat16(v);
    Hins[(size_t)(bg*16+batch)*(NSTEPS*HH) + 0*HH + col] = v;
  }
  __syncthreads();
  int p = 0;
  for (int s=1; s<NSTEPS; s++){
    f32x4 acc = {};
    #pragma unroll
    for (int kc=0; kc<8; kc++){
      short8 a = *(const short8*)&xb[p][r16*264 + kc*32 + quad*8];
      short8 b = *(const short8*)&Wl[col*264 + kc*32 + quad*8];
      acc = __builtin_amdgcn_mfma_f32_16x16x32_bf16(a, b, acc, 0,0,0);
    }
    #pragma unroll
    for (int r=0;r<4;r++){
      int batch = quad*4 + r;
      float v = fmaxf(qp[r] + bihv + acc[r] + bhhv, 0.f);
      xb[p^1][batch*264 + col] = __float2bfloat16(v);
      Hins[(size_t)(bg*16+batch)*(NSTEPS*HH) + s*HH + col] = v;
    }
    p ^= 1;
    __syncthreads();
  }
}

// ---------------- small utility kernels ----------------
__global__ void cvt_bf16_k(const float* __restrict__ src, __hip_bfloat16* __restrict__ dst, int n){
  int i = (blockIdx.x*256 + threadIdx.x)*4;
  if (i >= n) return;
  float4 v = *(const float4*)(src + i);
  dst[i]   = __float2bfloat16(v.x);
  dst[i+1] = __float2bfloat16(v.y);
  dst[i+2] = __float2bfloat16(v.z);
  dst[i+3] = __float2bfloat16(v.w);
}

__global__ void tr_cvt_k(const float* __restrict__ src, __hip_bfloat16* __restrict__ dst, int R, int Ccols){
  int idx = blockIdx.x*256 + threadIdx.x;
  if (idx >= R*Ccols) return;
  int r = idx / Ccols, c = idx % Ccols;
  dst[(size_t)c*R + r] = __float2bfloat16(src[idx]);
}

__global__ void build_cb_k(const float* __restrict__ vocab, const float* __restrict__ de,
                           __hip_bfloat16* __restrict__ Cb){
  int idx = blockIdx.x*256 + threadIdx.x;
  if (idx >= VPAD*HH) return;
  int v = idx >> 8, h = idx & 255;
  float x = (v < VV) ? vocab[(size_t)v*HH + h] : (v == VV ? de[h] : 0.f);
  Cb[idx] = __float2bfloat16(x);
}

__global__ void build_vt_k(const float* __restrict__ vocab, __hip_bfloat16* __restrict__ VT){
  int idx = blockIdx.x*256 + threadIdx.x;
  if (idx >= HH*KPAD) return;
  int h = idx / KPAD, v = idx % KPAD;
  VT[idx] = __float2bfloat16(v < VV ? vocab[(size_t)v*HH + h] : 0.f);
}

__global__ void bsum_k(const float* a, const float* b, float* o){
  int i = blockIdx.x*256 + threadIdx.x;
  if (i < 4*HH) o[i] = a[i] + b[i];
}

__global__ void init_k(float* dist, float* s_rel){
  int idx = blockIdx.x*256 + threadIdx.x;
  if (idx < NN){ dist[idx] = 1.f/150.f; s_rel[idx] = 0.f; }
}

__global__ void zero_k(float* p, int n){
  int idx = blockIdx.x*256 + threadIdx.x;
  if (idx < n) p[idx] = 0.f;
}

__global__ void inv_k(float* p, int n){
  int idx = blockIdx.x*256 + threadIdx.x;
  if (idx < n) p[idx] = 1.f/p[idx];
}

__global__ void vtag_epi_k(float* __restrict__ Vtag, const float* __restrict__ e_def,
                           const float* __restrict__ inv_s, const float* __restrict__ words){
  int r = blockIdx.x, h = threadIdx.x;
  size_t o = (size_t)r*HH + h;
  Vtag[o] += e_def[r]*inv_s[r]*words[o];
}

// attention per graph
__global__ __launch_bounds__(256) void attention_k(const float* __restrict__ Vtag,
                                                   const float* __restrict__ Hins,
                                                   const int* __restrict__ lengths,
                                                   float* __restrict__ R){
  __shared__ float Vl[LL][HH];
  __shared__ float Hn[NSTEPS][HH];
  __shared__ float att[NSTEPS][LL];
  int b = blockIdx.x, tid = threadIdx.x;
  for (int idx=tid; idx<LL*HH; idx+=256){ int l=idx>>8, h=idx&255; Vl[l][h] = Vtag[((size_t)b*LL+l)*HH + h]; }
  for (int idx=tid; idx<NSTEPS*HH; idx+=256){ Hn[idx>>8][idx&255] = Hins[(size_t)b*(NSTEPS*HH) + idx]; }
  __syncthreads();
  if (tid < NSTEPS*LL){
    int n2 = tid>>4, l = tid&15;
    float s = 0.f;
    for (int k=0;k<HH;k++) s += Hn[n2][k]*Vl[l][k];
    att[n2][l] = s;
  }
  __syncthreads();
  int len = lengths[b];
  if (tid < NSTEPS){
    float m = -1e30f;
    for (int l=0;l<len;l++) m = fmaxf(m, att[tid][l]);
    float s = 0.f;
    for (int l=0;l<LL;l++){ float e = (l<len)? expf(att[tid][l]-m) : 0.f; att[tid][l]=e; s+=e; }
    float inv = 1.f/s;
    for (int l=0;l<LL;l++) att[tid][l] *= inv;
  }
  __syncthreads();
  {
    int n2 = tid>>6, h0 = (tid&63)*4;
    float r0=0,r1=0,r2=0,r3=0;
    for (int l=0;l<LL;l++){
      float w = att[n2][l];
      r0 += w*Vl[l][h0]; r1 += w*Vl[l][h0+1]; r2 += w*Vl[l][h0+2]; r3 += w*Vl[l][h0+3];
    }
    float* o = R + (size_t)b*(NSTEPS*HH) + n2*HH + h0;
    o[0]=r0; o[1]=r1; o[2]=r2; o[3]=r3;
  }
}

// prop_sim for ALL steps: psa[s][b][4]
__global__ __launch_bounds__(256) void prop_sim_all_k(const float* __restrict__ R,
                                                      const float* __restrict__ pe,
                                                      float* __restrict__ psa){
  __shared__ float sp[4];
  int gb = blockIdx.x;
  int s = gb >> 8, b = gb & 255;
  int tid = threadIdx.x;
  int p = tid>>6, lane = tid&63;
  const float* instr = R + (size_t)b*(NSTEPS*HH) + s*HH;
  float v = 0.f;
  for (int h=lane; h<HH; h+=64) v += instr[h]*pe[p*HH+h];
  v = wred_sum(v);
  if (lane==0) sp[p] = v;
  __syncthreads();
  if (tid==0){
    float m = fmaxf(fmaxf(sp[0],sp[1]),fmaxf(sp[2],sp[3]));
    float e0=expf(sp[0]-m), e1=expf(sp[1]-m), e2=expf(sp[2]-m), e3=expf(sp[3]-m);
    float ss = e0+e1+e2+e3;
    float* o = psa + (size_t)s*BB*4 + b*4;
    o[0]=e0/ss; o[1]=e1/ss; o[2]=e2/ss; o[3]=e3/ss;
  }
}

// K1: node s_state (wave per node) + edge w[e]-scalar scatter into s_rel (wave per edge)
__global__ __launch_bounds__(256) void nsm_scores_k(
    const __hip_bfloat16* __restrict__ Tf, const __hip_bfloat16* __restrict__ ET,
    const float* __restrict__ R, const float* __restrict__ psa_s,
    const float* __restrict__ W_state, const float* __restrict__ Wr,
    const float* __restrict__ dist, const int* __restrict__ esrc, const int* __restrict__ edst,
    float* __restrict__ s_state, float* __restrict__ s_rel, int step)
{
  const int wave = threadIdx.x >> 6, lane = threadIdx.x & 63;
  const int h0 = lane*4;
  if (blockIdx.x < NN/4){
    int n = blockIdx.x*4 + wave;
    int g = n / NPG;
    const float* instr = R + (size_t)g*(NSTEPS*HH) + step*HH;
    float ps0 = psa_s[g*4], ps1 = psa_s[g*4+1], ps2 = psa_s[g*4+2];
    const unsigned short* t = (const unsigned short*)(Tf + (size_t)n*(3*HH));
    ushort4 t0 = *(const ushort4*)(t + h0);
    ushort4 t1 = *(const ushort4*)(t + HH + h0);
    ushort4 t2 = *(const ushort4*)(t + 2*HH + h0);
    float4 iv = *(const float4*)(instr + h0);
    float4 wv = *(const float4*)(W_state + h0);
    float acc;
    acc  = eluf(iv.x*(ps0*b2f(t0.x)+ps1*b2f(t1.x)+ps2*b2f(t2.x)))*wv.x;
    acc += eluf(iv.y*(ps0*b2f(t0.y)+ps1*b2f(t1.y)+ps2*b2f(t2.y)))*wv.y;
    acc += eluf(iv.z*(ps0*b2f(t0.z)+ps1*b2f(t1.z)+ps2*b2f(t2.z)))*wv.z;
    acc += eluf(iv.w*(ps0*b2f(t0.w)+ps1*b2f(t1.w)+ps2*b2f(t2.w)))*wv.w;
    acc = wred_sum(acc);
    if (lane==0) s_state[n] = acc;
  } else {
    int e = (blockIdx.x - NN/4)*4 + wave;
    int b = e / (NPG*DEG);
    const float* instr = R + (size_t)b*(NSTEPS*HH) + step*HH;
    const unsigned short* et = (const unsigned short*)(ET + (size_t)e*HH);
    ushort4 ev = *(const ushort4*)(et + h0);
    float4 iv = *(const float4*)(instr + h0);
    float4 wv = *(const float4*)(Wr + h0);
    float acc;
    acc  = eluf(iv.x*b2f(ev.x))*wv.x;
    acc += eluf(iv.y*b2f(ev.y))*wv.y;
    acc += eluf(iv.z*b2f(ev.z))*wv.z;
    acc += eluf(iv.w*b2f(ev.w))*wv.w;
    acc = wred_sum(acc);
    if (lane==0) atomicAdd(&s_rel[edst[e]], dist[esrc[e]]*acc);
  }
}

// K2: per-graph — both segment softmaxes + dist update; zeroes s_rel for next step
__global__ __launch_bounds__(256) void nsm_update_k(
    const float* __restrict__ s_state, float* __restrict__ s_rel,
    const float* __restrict__ psa_s, float* __restrict__ dist)
{
  __shared__ float sh[4];
  int b = blockIdx.x, i = threadIdx.x;
  bool ok = (i < NPG);
  float ss = ok ? s_state[b*NPG + i] : -1e30f;
  float sr = ok ? s_rel[b*NPG + i]   : -1e30f;
  float m1 = block_max256(ss, sh);
  float e1 = ok ? expf(ss - m1) : 0.f;
  float d1 = block_sum256(e1, sh);
  float m2 = block_max256(sr, sh);
  float e2 = ok ? expf(sr - m2) : 0.f;
  float d2 = block_sum256(e2, sh);
  if (ok){
    float pst = e1/d1, prl = e2/d2;
    float r = psa_s[b*4+3];
    dist[b*NPG + i] = r*prl + (1.f-r)*pst;
    s_rel[b*NPG + i] = 0.f;
  }
}

__global__ __launch_bounds__(256) void final_agg_k(const float* __restrict__ na, const float* __restrict__ dist,
                                                   const float* __restrict__ ps, float* __restrict__ aggregated){
  int b = blockIdx.x, h = threadIdx.x;
  float ps0 = ps[b*4+0], ps1 = ps[b*4+1], ps2 = ps[b*4+2];
  float acc = 0.f;
  for (int i=0;i<NPG;i++){
    int n = b*NPG + i;
    float d = dist[n];
    const float* a = na + (size_t)n*(3*HH);
    acc += d*(ps0*a[h] + ps1*a[HH+h] + ps2*a[2*HH+h]);
  }
  aggregated[b*HH + h] = acc;
}

__global__ void qa_build_k(const float* __restrict__ Q, const float* __restrict__ aggregated,
                           float* __restrict__ QA){
  int idx = blockIdx.x*256 + threadIdx.x;
  if (idx >= BB*2*HH) return;
  int b = idx >> 9, k = idx & 511;
  QA[idx] = (k < HH) ? Q[b*HH + k] : aggregated[b*HH + (k-HH)];
}

// ---------------- host ----------------
extern "C" void kernel_launch(void* const* d_in, const int* in_sizes, int n_in,
                              void* d_out, int out_size, void* d_ws, size_t ws_size,
                              hipStream_t stream) {
  (void)in_sizes; (void)n_in; (void)out_size; (void)ws_size;
  const float* questions     = (const float*)d_in[0];
  const float* node_attrs    = (const float*)d_in[1];
  const float* edge_attrs    = (const float*)d_in[2];
  const float* vocab         = (const float*)d_in[3];
  const float* default_embed = (const float*)d_in[4];
  const float* W_norm        = (const float*)d_in[5];
  const float* lstm_Wih      = (const float*)d_in[6];   // (1024,256) row-major == Bt
  const float* lstm_Whh      = (const float*)d_in[7];   // (1024,256) row-major == Bt
  const float* lstm_bih      = (const float*)d_in[8];
  const float* lstm_bhh      = (const float*)d_in[9];
  const float* rnn_Wih       = (const float*)d_in[10];  // (256,256) row-major == Bt
  const float* rnn_Whh       = (const float*)d_in[11];
  const float* rnn_bih       = (const float*)d_in[12];
  const float* rnn_bhh       = (const float*)d_in[13];
  const float* prop_embeds   = (const float*)d_in[14];
  const float* Ws_property   = (const float*)d_in[15];
  const float* W_state       = (const float*)d_in[16];
  const float* W_relation    = (const float*)d_in[17];
  const float* lin_W         = (const float*)d_in[18];  // (2000,512) row-major == Bt
  const float* lin_b         = (const float*)d_in[19];
  const int*   lengths       = (const int*)d_in[20];
  const int*   edge_src      = (const int*)d_in[23];
  const int*   edge_dst      = (const int*)d_in[24];
  float* out = (float*)d_out;

  char* base = (char*)d_ws;
  size_t off = 0;
  auto alloc = [&](size_t nbytes)->void*{
    void* p = base + off;
    off += (nbytes + 255) & ~(size_t)255;
    return p;
  };

  __hip_bfloat16* qbf     = (__hip_bfloat16*)alloc((size_t)BL*HH*2);
  __hip_bfloat16* WnT_bf  = (__hip_bfloat16*)alloc((size_t)HH*HH*2);
  __hip_bfloat16* xw_bf   = (__hip_bfloat16*)alloc((size_t)BL*HH*2);
  __hip_bfloat16* Cbv     = (__hip_bfloat16*)alloc((size_t)VPAD*HH*2);
  __hip_bfloat16* vT_bf   = (__hip_bfloat16*)alloc((size_t)HH*KPAD*2);
  __hip_bfloat16* Whh_bf  = (__hip_bfloat16*)alloc((size_t)4*HH*HH*2);
  __hip_bfloat16* rWih_bf = (__hip_bfloat16*)alloc((size_t)HH*HH*2);
  __hip_bfloat16* rWhh_bf = (__hip_bfloat16*)alloc((size_t)HH*HH*2);
  __hip_bfloat16* h_bf    = (__hip_bfloat16*)alloc((size_t)BB*HH*2);
  float* e_def    = (float*)alloc((size_t)BL*4);
  float* row_sum  = (float*)alloc((size_t)BL*4);
  float* Vtag     = (float*)alloc((size_t)BL*HH*4);
  float* bsum     = (float*)alloc((size_t)4*HH*4);
  float* h_buf    = (float*)alloc((size_t)BB*HH*4);
  float* Hins     = (float*)alloc((size_t)BB*NSTEPS*HH*4);
  float* R        = (float*)alloc((size_t)BB*NSTEPS*HH*4);
  float* psa      = (float*)alloc((size_t)NSTEPS*BB*4*4);
  float* s_state  = (float*)alloc((size_t)NN*4);
  float* s_rel    = (float*)alloc((size_t)NN*4);
  float* dist     = (float*)alloc((size_t)NN*4);
  float* aggregated = (float*)alloc((size_t)BB*HH*4);
  float* QA       = (float*)alloc((size_t)BB*2*HH*4);
  __hip_bfloat16* Pm_bf = (__hip_bfloat16*)alloc((size_t)BL*KPAD*2);
  // Tf region (59MB bf16); gX (16.8MB f32) aliases its start (disjoint in time)
  char*  TfR      = (char*)alloc((size_t)NN*3*HH*2);
  __hip_bfloat16* Tf = (__hip_bfloat16*)TfR;
  float* gX          = (float*)TfR;
  __hip_bfloat16* ET = (__hip_bfloat16*)alloc((size_t)EE*HH*2);

  // ---- setup ----
  init_k<<<(NN+255)/256, 256, 0, stream>>>(dist, s_rel);
  cvt_bf16_k<<<(BL*HH/4+255)/256, 256, 0, stream>>>(questions, qbf, BL*HH);
  tr_cvt_k<<<(HH*HH+255)/256, 256, 0, stream>>>(W_norm, WnT_bf, HH, HH);
  build_cb_k<<<(VPAD*HH+255)/256, 256, 0, stream>>>(vocab, default_embed, Cbv);
  build_vt_k<<<(HH*KPAD+255)/256, 256, 0, stream>>>(vocab, vT_bf);
  cvt_bf16_k<<<(4*HH*HH/4+255)/256, 256, 0, stream>>>(lstm_Whh, Whh_bf, 4*HH*HH);
  cvt_bf16_k<<<(HH*HH/4+255)/256, 256, 0, stream>>>(rnn_Wih, rWih_bf, HH*HH);
  cvt_bf16_k<<<(HH*HH/4+255)/256, 256, 0, stream>>>(rnn_Whh, rWhh_bf, HH*HH);
  bsum_k<<<(4*HH+255)/256, 256, 0, stream>>>(lstm_bih, lstm_bhh, bsum);
  zero_k<<<(BL+255)/256, 256, 0, stream>>>(row_sum, BL);
  zero_k<<<(BL*HH+255)/256, 256, 0, stream>>>(Vtag, BL*HH);

  // ---- phase A: word embedding ----
  mfma_bt_bf16_k<1><<<dim3(2,32,1), 256, 0, stream>>>(qbf, WnT_bf, nullptr, xw_bf,
      HH, HH, HH, HH, HH/32, HH/32, nullptr, nullptr);
  gemm_exp_k<<<dim3(VPAD/128, BL/128, 1), 256, 0, stream>>>(xw_bf, Cbv, Pm_bf, row_sum, e_def);
  inv_k<<<(BL+255)/256, 256, 0, stream>>>(row_sum, BL);
  mfma_bt_bf16_k<2><<<dim3(HH/128, BL/128, 8), 256, 0, stream>>>(
      Pm_bf, vT_bf, Vtag, nullptr, KPAD, KPAD, HH, HH, KPAD/32, 20, nullptr, row_sum);
  vtag_epi_k<<<BL, HH, 0, stream>>>(Vtag, e_def, row_sum, questions);

  // ---- phase B: LSTM encoder ----
  mfma_bt_f32_k<0><<<dim3(8,32,1), 256, 0, stream>>>(Vtag, lstm_Wih, gX, nullptr,
      HH, HH, 4*HH, 4*HH, HH/32, bsum);
  lstm_persist_k<<<16, 1024, 0, stream>>>(gX, Whh_bf, lengths, h_buf, h_bf);

  // ---- phase C: decoder RNN ----
  dec_persist_k<<<16, 1024, 0, stream>>>(h_bf, rWih_bf, rWhh_bf, rnn_bih, rnn_bhh, Hins);

  // ---- phase D: attention -> R; prop_sim for all steps ----
  attention_k<<<BB, 256, 0, stream>>>(Vtag, Hins, lengths, R);
  prop_sim_all_k<<<NSTEPS*BB, 256, 0, stream>>>(R, prop_embeds, psa);

  // ---- phase E: step-invariant heavy GEMMs (bf16 out). Clobbers gX (dead). ----
  for (int p=0; p<3; p++)
    mfma_bt_f32_k<1><<<dim3(2,NN/128,1), 256, 0, stream>>>(
        node_attrs + (size_t)p*HH, Ws_property + (size_t)p*HH*HH,
        nullptr, Tf + (size_t)p*HH, 3*HH, HH, 3*HH, HH, HH/32, nullptr);
  mfma_bt_f32_k<1><<<dim3(2,EE/128,1), 256, 0, stream>>>(
      edge_attrs, Ws_property + (size_t)3*HH*HH,
      nullptr, ET, HH, HH, HH, HH, HH/32, nullptr);

  // ---- phase F: 4-step NSM loop ----
  for (int s=0; s<NSTEPS; s++){
    const float* psa_s = psa + (size_t)s*BB*4;
    nsm_scores_k<<<NN/4 + EE/4, 256, 0, stream>>>(
        Tf, ET, R, psa_s, W_state, W_relation, dist, edge_src, edge_dst,
        s_state, s_rel, s);
    nsm_update_k<<<BB, 256, 0, stream>>>(s_state, s_rel, psa_s, dist);
  }

  // ---- phase G: readout ----
  final_agg_k<<<BB, 256, 0, stream>>>(node_attrs, dist, psa + (size_t)3*BB*4, aggregated);
  qa_build_k<<<(BB*2*HH+255)/256, 256, 0, stream>>>(h_buf, aggregated, QA);
  mfma_bt_f32_k<0><<<dim3(16,2,1), 256, 0, stream>>>(QA, lin_W, out, nullptr,
      2*HH, 2*HH, OUTD, OUTD, 2*HH/32, lin_b);
}

// Round 2
// 1100.114 us; speedup vs baseline: 1.1311x; 1.0467x over previous
//
#include <hip/hip_runtime.h>
#include <hip/hip_bf16.h>
#include <math.h>

// Problem constants
#define BB 256
#define LL 16
#define HH 256
#define VV 5000
#define NPG 150
#define DEG 4
#define NSTEPS 4
#define OUTD 2000
#define NN (BB*NPG)      // 38400
#define EE (BB*NPG*DEG)  // 153600
#define BL (BB*LL)       // 4096
#define VPAD 5120        // logits column pad (40*128)
#define KPAD 5024        // Pm K pad (157*32)

// ---------------- helpers ----------------
__device__ __forceinline__ float wred_sum(float v){
  #pragma unroll
  for(int o=32;o;o>>=1) v += __shfl_down(v,o,64);
  return v;
}
__device__ __forceinline__ float wred_max(float v){
  #pragma unroll
  for(int o=32;o;o>>=1) v = fmaxf(v,__shfl_down(v,o,64));
  return v;
}
__device__ __forceinline__ float block_sum256(float v, float* sh){
  v = wred_sum(v);
  __syncthreads();
  if((threadIdx.x&63)==0) sh[threadIdx.x>>6]=v;
  __syncthreads();
  return sh[0]+sh[1]+sh[2]+sh[3];
}
__device__ __forceinline__ float block_max256(float v, float* sh){
  v = wred_max(v);
  __syncthreads();
  if((threadIdx.x&63)==0) sh[threadIdx.x>>6]=v;
  __syncthreads();
  return fmaxf(fmaxf(sh[0],sh[1]),fmaxf(sh[2],sh[3]));
}
__device__ __forceinline__ float eluf(float x){ return x>0.f ? x : expm1f(x); }
__device__ __forceinline__ float sigf(float x){ return 1.f/(1.f+expf(-x)); }
// fast saturating sigmoid/tanh (v_exp + v_rcp; ~1e-7 rel err, exact limits)
__device__ __forceinline__ float fsig(float x){
  return __builtin_amdgcn_rcpf(1.f + __expf(-x));
}
__device__ __forceinline__ float ftanh(float x){
  return 1.f - 2.f*__builtin_amdgcn_rcpf(1.f + __expf(2.f*x));
}
__device__ __forceinline__ float b2f(unsigned short s){
  union{float f; unsigned int u;} x; x.u = ((unsigned int)s)<<16; return x.f;
}
__device__ __forceinline__ unsigned short f2bf_bits(float x){
  union { __hip_bfloat16 h; unsigned short s; } u; u.h = __float2bfloat16(x); return u.s;
}

// async global->LDS 16B (gfx950), lds dest = wave-uniform base + lane*16
__device__ __forceinline__ void async16(void* lds, const void* g){
  __builtin_amdgcn_global_load_lds(
      (const __attribute__((address_space(1))) unsigned int*)g,
      (__attribute__((address_space(3))) unsigned int*)lds, 16, 0, 0);
}

typedef __attribute__((ext_vector_type(8))) short short8;
typedef __attribute__((ext_vector_type(4))) float f32x4;

__device__ __forceinline__ short8 pack8(float4 a, float4 b){
  short8 r;
  r[0]=(short)f2bf_bits(a.x); r[1]=(short)f2bf_bits(a.y);
  r[2]=(short)f2bf_bits(a.z); r[3]=(short)f2bf_bits(a.w);
  r[4]=(short)f2bf_bits(b.x); r[5]=(short)f2bf_bits(b.y);
  r[6]=(short)f2bf_bits(b.z); r[7]=(short)f2bf_bits(b.w);
  return r;
}

// =======================================================================
// MFMA GEMM, C[m,n] = sum_k A[m,k]*Bt[n,k].  128x128 tile, BK=32, 4 waves.
// EPI: 0 = f32 store (+bias, col<Nreal), 1 = bf16 store, 2 = f32 atomicAdd
//      (EPI 2: optional per-row scale rscale[row])
// =======================================================================
template<int EPI>
__global__ __launch_bounds__(256) void mfma_bt_bf16_k(
    const __hip_bfloat16* __restrict__ A, const __hip_bfloat16* __restrict__ Bt,
    float* __restrict__ Cf, __hip_bfloat16* __restrict__ Cb,
    int lda, int ldb, int ldc, int Nreal,
    int kItersTotal, int kPerSplit, const float* __restrict__ bias,
    const float* __restrict__ rscale)
{
  __shared__ __hip_bfloat16 As[128*32];
  __shared__ __hip_bfloat16 Bs[128*32];
  const int bm = blockIdx.y*128, bn = blockIdx.x*128;
  const int tid = threadIdx.x;
  int k0 = blockIdx.z * kPerSplit;
  int k1 = k0 + kPerSplit; if (k1 > kItersTotal) k1 = kItersTotal;
  const int lane = tid & 63, wave = tid >> 6;
  const int quad = lane >> 4, r16 = lane & 15;
  const int wr = wave >> 1, wc = wave & 1;
  f32x4 acc[4][4] = {};
  const int c0 = tid, c1 = tid + 256;
  const int ar0 = c0 >> 2, ak0 = (c0 & 3)*8;
  const int ar1 = c1 >> 2, ak1 = (c1 & 3)*8;
  const __hip_bfloat16* Ab = A + (size_t)bm*lda;
  const __hip_bfloat16* Bb = Bt + (size_t)bn*ldb;
  for (int kk = k0; kk < k1; ++kk){
    const int kb = kk*32;
    async16(&As[c0*8], Ab + (size_t)ar0*lda + kb + ak0);
    async16(&As[c1*8], Ab + (size_t)ar1*lda + kb + ak1);
    async16(&Bs[c0*8], Bb + (size_t)ar0*ldb + kb + ak0);
    async16(&Bs[c1*8], Bb + (size_t)ar1*ldb + kb + ak1);
    __syncthreads();
    short8 av[4], bv[4];
    #pragma unroll
    for (int i=0;i<4;i++){
      av[i] = *(const short8*)&As[(wr*64 + i*16 + r16)*32 + quad*8];
      bv[i] = *(const short8*)&Bs[(wc*64 + i*16 + r16)*32 + quad*8];
    }
    #pragma unroll
    for (int i=0;i<4;i++)
      #pragma unroll
      for (int j=0;j<4;j++)
        acc[i][j] = __builtin_amdgcn_mfma_f32_16x16x32_bf16(av[i], bv[j], acc[i][j], 0,0,0);
    __syncthreads();
  }
  #pragma unroll
  for (int i=0;i<4;i++){
    int row = bm + wr*64 + i*16 + quad*4;
    #pragma unroll
    for (int j=0;j<4;j++){
      int col = bn + wc*64 + j*16 + r16;
      if (col >= Nreal) continue;
      #pragma unroll
      for (int r=0;r<4;r++){
        float v = acc[i][j][r];
        if (EPI==0){ if (bias) v += bias[col]; Cf[(size_t)(row+r)*ldc + col] = v; }
        else if (EPI==1){ Cb[(size_t)(row+r)*ldc + col] = __float2bfloat16(v); }
        else { if (rscale) v *= rscale[row+r]; atomicAdd(&Cf[(size_t)(row+r)*ldc + col], v); }
      }
    }
  }
}

// Same GEMM, f32 global operands, packed bf16 staging (2x float4 -> 1x b128 LDS write)
template<int EPI>
__global__ __launch_bounds__(256) void mfma_bt_f32_k(
    const float* __restrict__ A, const float* __restrict__ Bt,
    float* __restrict__ Cf, __hip_bfloat16* __restrict__ Cb,
    int lda, int ldb, int ldc, int Nreal,
    int kIters, const float* __restrict__ bias)
{
  __shared__ __hip_bfloat16 As[128*32];
  __shared__ __hip_bfloat16 Bs[128*32];
  const int bm = blockIdx.y*128, bn = blockIdx.x*128;
  const int tid = threadIdx.x;
  const int lane = tid & 63, wave = tid >> 6;
  const int quad = lane >> 4, r16 = lane & 15;
  const int wr = wave >> 1, wc = wave & 1;
  f32x4 acc[4][4] = {};
  for (int kk = 0; kk < kIters; ++kk){
    const int kb = kk*32;
    #pragma unroll
    for (int i=0;i<2;i++){
      int c = tid + i*256;
      int row = c >> 2, k0 = (c & 3)*8;
      const float* src = A + (size_t)(bm+row)*lda + kb + k0;
      float4 v0 = *(const float4*)(src);
      float4 v1 = *(const float4*)(src+4);
      *(short8*)&As[row*32 + k0] = pack8(v0, v1);
    }
    #pragma unroll
    for (int i=0;i<2;i++){
      int c = tid + i*256;
      int row = c >> 2, k0 = (c & 3)*8;
      float4 v0 = {0.f,0.f,0.f,0.f}, v1 = {0.f,0.f,0.f,0.f};
      if (bn + row < Nreal){
        const float* src = Bt + (size_t)(bn+row)*ldb + kb + k0;
        v0 = *(const float4*)(src);
        v1 = *(const float4*)(src+4);
      }
      *(short8*)&Bs[row*32 + k0] = pack8(v0, v1);
    }
    __syncthreads();
    short8 av[4], bv[4];
    #pragma unroll
    for (int i=0;i<4;i++){
      av[i] = *(const short8*)&As[(wr*64 + i*16 + r16)*32 + quad*8];
      bv[i] = *(const short8*)&Bs[(wc*64 + i*16 + r16)*32 + quad*8];
    }
    #pragma unroll
    for (int i=0;i<4;i++)
      #pragma unroll
      for (int j=0;j<4;j++)
        acc[i][j] = __builtin_amdgcn_mfma_f32_16x16x32_bf16(av[i], bv[j], acc[i][j], 0,0,0);
    __syncthreads();
  }
  #pragma unroll
  for (int i=0;i<4;i++){
    int row = bm + wr*64 + i*16 + quad*4;
    #pragma unroll
    for (int j=0;j<4;j++){
      int col = bn + wc*64 + j*16 + r16;
      if (col >= Nreal) continue;
      #pragma unroll
      for (int r=0;r<4;r++){
        float v = acc[i][j][r];
        if (EPI==0){ if (bias) v += bias[col]; Cf[(size_t)(row+r)*ldc + col] = v; }
        else { Cb[(size_t)(row+r)*ldc + col] = __float2bfloat16(v); }
      }
    }
  }
}

// Fused logits GEMM + exp epilogue: Pm[r][c] = exp(logit) (unnormalized, bf16),
// row_sum[r] += partial sums (cols 0..VV), e_def[r] = exp(logit[VV]).
__global__ __launch_bounds__(256) void gemm_exp_k(
    const __hip_bfloat16* __restrict__ A, const __hip_bfloat16* __restrict__ Bt,
    __hip_bfloat16* __restrict__ Pm, float* __restrict__ row_sum,
    float* __restrict__ e_def)
{
  __shared__ __hip_bfloat16 As[128*32];
  __shared__ __hip_bfloat16 Bs[128*32];
  const int bm = blockIdx.y*128, bn = blockIdx.x*128;
  const int tid = threadIdx.x;
  const int lane = tid & 63, wave = tid >> 6;
  const int quad = lane >> 4, r16 = lane & 15;
  const int wr = wave >> 1, wc = wave & 1;
  f32x4 acc[4][4] = {};
  const int c0 = tid, c1 = tid + 256;
  const int ar0 = c0 >> 2, ak0 = (c0 & 3)*8;
  const int ar1 = c1 >> 2, ak1 = (c1 & 3)*8;
  const __hip_bfloat16* Ab = A + (size_t)bm*HH;
  const __hip_bfloat16* Bb = Bt + (size_t)bn*HH;
  for (int kk = 0; kk < HH/32; ++kk){
    const int kb = kk*32;
    async16(&As[c0*8], Ab + (size_t)ar0*HH + kb + ak0);
    async16(&As[c1*8], Ab + (size_t)ar1*HH + kb + ak1);
    async16(&Bs[c0*8], Bb + (size_t)ar0*HH + kb + ak0);
    async16(&Bs[c1*8], Bb + (size_t)ar1*HH + kb + ak1);
    __syncthreads();
    short8 av[4], bv[4];
    #pragma unroll
    for (int i=0;i<4;i++){
      av[i] = *(const short8*)&As[(wr*64 + i*16 + r16)*32 + quad*8];
      bv[i] = *(const short8*)&Bs[(wc*64 + i*16 + r16)*32 + quad*8];
    }
    #pragma unroll
    for (int i=0;i<4;i++)
      #pragma unroll
      for (int j=0;j<4;j++)
        acc[i][j] = __builtin_amdgcn_mfma_f32_16x16x32_bf16(av[i], bv[j], acc[i][j], 0,0,0);
    __syncthreads();
  }
  #pragma unroll
  for (int i=0;i<4;i++){
    int rowb = bm + wr*64 + i*16 + quad*4;
    float rsum[4] = {0.f,0.f,0.f,0.f};
    #pragma unroll
    for (int j=0;j<4;j++){
      int col = bn + wc*64 + j*16 + r16;
      #pragma unroll
      for (int r=0;r<4;r++){
        float e = (col <= VV) ? expf(acc[i][j][r]) : 0.f;
        rsum[r] += e;
        if (col < KPAD) Pm[(size_t)(rowb+r)*KPAD + col] = __float2bfloat16(col < VV ? e : 0.f);
        if (col == VV) e_def[rowb+r] = e;
      }
    }
    #pragma unroll
    for (int r=0;r<4;r++){
      float s = rsum[r];
      s += __shfl_xor(s, 1, 64);
      s += __shfl_xor(s, 2, 64);
      s += __shfl_xor(s, 4, 64);
      s += __shfl_xor(s, 8, 64);
      if (r16 == 0) atomicAdd(&row_sum[rowb+r], s);
    }
  }
}

// =======================================================================
// Persistent batch-parallel LSTM, v3: 16 blocks x 1024 threads (16 waves).
// Wave w owns hidden units [16w,16w+16) for ALL FOUR gates.
// Weight placement per wave (rows = 4 gate-blocks of 16, cols = K=256):
//   - kc 0..2 (cols 0..95):   registers, ALL waves (12 x short8 = 48 VGPR,
//     loaded once -> zero steady-state traffic, forces VGPR>64 so the
//     allocator can pipeline the remaining stream loads)
//   - kc 3..7 (cols 96..255): LDS Wl for waves 0..5 (384 rows x 328B stride)
//   - kc 3..7 waves 6..15:    streamed from L2 each step (200KB/step/CU)
// gx loads hoisted to top of step (independent of recurrence -> hidden
// under the MFMA phase). Gate math uses fast saturating sig/tanh.
// =======================================================================
__global__ __launch_bounds__(1024) void lstm_persist_k(
    const float* __restrict__ gX, const __hip_bfloat16* __restrict__ Whh_bf,
    const int* __restrict__ lengths,
    float* __restrict__ h_out, __hip_bfloat16* __restrict__ hbf_out)
{
  __shared__ __hip_bfloat16 Wl[384*164];      // kc3..7, waves 0..5 (125.9KB)
  __shared__ __hip_bfloat16 hbuf[2][16*264];  // double-buffered recurrent h
  const int bg = blockIdx.x, tid = threadIdx.x;
  const int lane = tid & 63, w = tid >> 6;
  const int quad = lane >> 4, r16 = lane & 15;
  const int hb = w*16;
  // preload Wl: row = w*64 + g*16 + rr  <->  Whh row g*256 + w*16 + rr, cols 96..255
  for (int idx = tid; idx < 384*20; idx += 1024){
    int row = idx / 20, c8 = (idx % 20)*8;
    int ww = row >> 6, g = (row >> 4) & 3, rr = row & 15;
    *(short8*)&Wl[row*164 + c8] =
        *(const short8*)&Whh_bf[((size_t)(g*256 + ww*16 + rr))*256 + 96 + c8];
  }
  // register-resident weights: kc 0..2, all waves
  short8 rW[3][4];
  #pragma unroll
  for (int kc=0; kc<3; kc++)
    #pragma unroll
    for (int g=0; g<4; g++)
      rW[kc][g] = *(const short8*)&Whh_bf[((size_t)(g*256 + hb + r16))*256 + kc*32 + quad*8];
  for (int i = tid; i < 16*264; i += 1024) hbuf[0][i] = __float2bfloat16(0.f);
  int lenr[4];
  #pragma unroll
  for (int r=0;r<4;r++) lenr[r] = lengths[bg*16 + quad*4 + r];
  __syncthreads();
  f32x4 cstate = {0.f,0.f,0.f,0.f};
  f32x4 hstate = {0.f,0.f,0.f,0.f};
  int p = 0;
  const float* gXb = gX + (size_t)bg*16*LL*(4*HH) + hb + r16;
  for (int t=0; t<LL; t++){
    // gx prefetch (independent of h_{t-1}; in flight across the MFMA phase)
    float gxv[4][4];
    #pragma unroll
    for (int r=0;r<4;r++)
      #pragma unroll
      for (int g=0;g<4;g++)
        gxv[r][g] = gXb[((size_t)((quad*4+r)*LL + t))*(4*HH) + g*HH];
    f32x4 acc[4] = {};
    const __hip_bfloat16* hr = hbuf[p];
    #pragma unroll
    for (int kc=0; kc<3; kc++){
      short8 a = *(const short8*)&hr[r16*264 + kc*32 + quad*8];
      #pragma unroll
      for (int g=0; g<4; g++)
        acc[g] = __builtin_amdgcn_mfma_f32_16x16x32_bf16(a, rW[kc][g], acc[g], 0,0,0);
    }
    if (w < 6){
      #pragma unroll
      for (int kc=3; kc<8; kc++){
        short8 a = *(const short8*)&hr[r16*264 + kc*32 + quad*8];
        #pragma unroll
        for (int g=0; g<4; g++){
          short8 b = *(const short8*)&Wl[(w*64 + g*16 + r16)*164 + (kc-3)*32 + quad*8];
          acc[g] = __builtin_amdgcn_mfma_f32_16x16x32_bf16(a, b, acc[g], 0,0,0);
        }
      }
    } else {
      #pragma unroll
      for (int kc=3; kc<8; kc++){
        short8 a = *(const short8*)&hr[r16*264 + kc*32 + quad*8];
        #pragma unroll
        for (int g=0; g<4; g++){
          short8 b = *(const short8*)&Whh_bf[((size_t)(g*256 + hb + r16))*256 + kc*32 + quad*8];
          acc[g] = __builtin_amdgcn_mfma_f32_16x16x32_bf16(a, b, acc[g], 0,0,0);
        }
      }
    }
    #pragma unroll
    for (int r=0;r<4;r++){
      int batch = quad*4 + r;
      float gi = acc[0][r] + gxv[r][0];
      float gf = acc[1][r] + gxv[r][1];
      float gc = acc[2][r] + gxv[r][2];
      float go = acc[3][r] + gxv[r][3];
      float cn = fsig(gf)*cstate[r] + fsig(gi)*ftanh(gc);
      float hn = fsig(go)*ftanh(cn);
      if (t < lenr[r]){ cstate[r] = cn; hstate[r] = hn; }
      hbuf[p^1][batch*264 + hb + r16] = __float2bfloat16(hstate[r]);
    }
    p ^= 1;
    __syncthreads();
  }
  #pragma unroll
  for (int r=0;r<4;r++){
    int batch = quad*4 + r;
    size_t o = (size_t)(bg*16+batch)*HH + hb + r16;
    h_out[o] = hstate[r];
    hbf_out[o] = __float2bfloat16(hstate[r]);
  }
}

// Persistent batch-parallel decoder RNN v2: 16 blocks x 1024 threads.
// Entire Whh (128KB) cached in LDS; qp and x-state in registers; step 0 has
// h=0 so its MFMA is skipped entirely.
__global__ __launch_bounds__(1024) void dec_persist_k(
    const __hip_bfloat16* __restrict__ Qbf, const __hip_bfloat16* __restrict__ Wih_bf,
    const __hip_bfloat16* __restrict__ Whh_bf,
    const float* __restrict__ bih, const float* __restrict__ bhh,
    float* __restrict__ Hins)
{
  __shared__ __hip_bfloat16 Wl[256*264];     // full Whh, 132KB
  __shared__ __hip_bfloat16 xb[2][16*264];
  const int bg = blockIdx.x, tid = threadIdx.x;
  const int lane = tid & 63, w = tid >> 6;
  const int quad = lane >> 4, r16 = lane & 15;
  const int col = w*16 + r16;
  for (int c = tid; c < 8192; c += 1024){
    int row = c >> 5, ci = (c & 31)*8;
    *(short8*)&Wl[row*264 + ci] = *(const short8*)&Whh_bf[(size_t)row*256 + ci];
  }
  // qp = Q @ Wih^T  (A rows straight from global; Wih streamed from L2 once)
  f32x4 qp = {};
  #pragma unroll
  for (int kc=0; kc<8; kc++){
    short8 a = *(const short8*)&Qbf[(size_t)(bg*16 + r16)*HH + kc*32 + quad*8];
    short8 b = *(const short8*)&Wih_bf[(size_t)col*HH + kc*32 + quad*8];
    qp = __builtin_amdgcn_mfma_f32_16x16x32_bf16(a, b, qp, 0,0,0);
  }
  const float bihv = bih[col], bhhv = bhh[col];
  __syncthreads();           // Wl ready
  // s = 0: hx=0 -> x = relu(qp + bih + bhh)
  #pragma unroll
  for (int r=0;r<4;r++){
    int batch = quad*4 + r;
    float v = fmaxf(qp[r] + bihv + bhhv, 0.f);
    xb[0][batch*264 + col] = __float2bfloat16(v);
    Hins[(size_t)(bg*16+batch)*(NSTEPS*HH) + 0*HH + col] = v;
  }
  __syncthreads();
  int p = 0;
  for (int s=1; s<NSTEPS; s++){
    f32x4 acc = {};
    #pragma unroll
    for (int kc=0; kc<8; kc++){
      short8 a = *(const short8*)&xb[p][r16*264 + kc*32 + quad*8];
      short8 b = *(const short8*)&Wl[col*264 + kc*32 + quad*8];
      acc = __builtin_amdgcn_mfma_f32_16x16x32_bf16(a, b, acc, 0,0,0);
    }
    #pragma unroll
    for (int r=0;r<4;r++){
      int batch = quad*4 + r;
      float v = fmaxf(qp[r] + bihv + acc[r] + bhhv, 0.f);
      xb[p^1][batch*264 + col] = __float2bfloat16(v);
      Hins[(size_t)(bg*16+batch)*(NSTEPS*HH) + s*HH + col] = v;
    }
    p ^= 1;
    __syncthreads();
  }
}

// ---------------- small utility kernels ----------------
__global__ void cvt_bf16_k(const float* __restrict__ src, __hip_bfloat16* __restrict__ dst, int n){
  int i = (blockIdx.x*256 + threadIdx.x)*4;
  if (i >= n) return;
  float4 v = *(const float4*)(src + i);
  dst[i]   = __float2bfloat16(v.x);
  dst[i+1] = __float2bfloat16(v.y);
  dst[i+2] = __float2bfloat16(v.z);
  dst[i+3] = __float2bfloat16(v.w);
}

__global__ void tr_cvt_k(const float* __restrict__ src, __hip_bfloat16* __restrict__ dst, int R, int Ccols){
  int idx = blockIdx.x*256 + threadIdx.x;
  if (idx >= R*Ccols) return;
  int r = idx / Ccols, c = idx % Ccols;
  dst[(size_t)c*R + r] = __float2bfloat16(src[idx]);
}

__global__ void build_cb_k(const float* __restrict__ vocab, const float* __restrict__ de,
                           __hip_bfloat16* __restrict__ Cb){
  int idx = blockIdx.x*256 + threadIdx.x;
  if (idx >= VPAD*HH) return;
  int v = idx >> 8, h = idx & 255;
  float x = (v < VV) ? vocab[(size_t)v*HH + h] : (v == VV ? de[h] : 0.f);
  Cb[idx] = __float2bfloat16(x);
}

__global__ void build_vt_k(const float* __restrict__ vocab, __hip_bfloat16* __restrict__ VT){
  int idx = blockIdx.x*256 + threadIdx.x;
  if (idx >= HH*KPAD) return;
  int h = idx / KPAD, v = idx % KPAD;
  VT[idx] = __float2bfloat16(v < VV ? vocab[(size_t)v*HH + h] : 0.f);
}

__global__ void bsum_k(const float* a, const float* b, float* o){
  int i = blockIdx.x*256 + threadIdx.x;
  if (i < 4*HH) o[i] = a[i] + b[i];
}

__global__ void init_k(float* dist, float* s_rel){
  int idx = blockIdx.x*256 + threadIdx.x;
  if (idx < NN){ dist[idx] = 1.f/150.f; s_rel[idx] = 0.f; }
}

__global__ void zero_k(float* p, int n){
  int idx = blockIdx.x*256 + threadIdx.x;
  if (idx < n) p[idx] = 0.f;
}

__global__ void inv_k(float* p, int n){
  int idx = blockIdx.x*256 + threadIdx.x;
  if (idx < n) p[idx] = 1.f/p[idx];
}

__global__ void vtag_epi_k(float* __restrict__ Vtag, const float* __restrict__ e_def,
                           const float* __restrict__ inv_s, const float* __restrict__ words){
  int r = blockIdx.x, h = threadIdx.x;
  size_t o = (size_t)r*HH + h;
  Vtag[o] += e_def[r]*inv_s[r]*words[o];
}

// attention per graph
__global__ __launch_bounds__(256) void attention_k(const float* __restrict__ Vtag,
                                                   const float* __restrict__ Hins,
                                                   const int* __restrict__ lengths,
                                                   float* __restrict__ R){
  __shared__ float Vl[LL][HH];
  __shared__ float Hn[NSTEPS][HH];
  __shared__ float att[NSTEPS][LL];
  int b = blockIdx.x, tid = threadIdx.x;
  for (int idx=tid; idx<LL*HH; idx+=256){ int l=idx>>8, h=idx&255; Vl[l][h] = Vtag[((size_t)b*LL+l)*HH + h]; }
  for (int idx=tid; idx<NSTEPS*HH; idx+=256){ Hn[idx>>8][idx&255] = Hins[(size_t)b*(NSTEPS*HH) + idx]; }
  __syncthreads();
  if (tid < NSTEPS*LL){
    int n2 = tid>>4, l = tid&15;
    float s = 0.f;
    for (int k=0;k<HH;k++) s += Hn[n2][k]*Vl[l][k];
    att[n2][l] = s;
  }
  __syncthreads();
  int len = lengths[b];
  if (tid < NSTEPS){
    float m = -1e30f;
    for (int l=0;l<len;l++) m = fmaxf(m, att[tid][l]);
    float s = 0.f;
    for (int l=0;l<LL;l++){ float e = (l<len)? expf(att[tid][l]-m) : 0.f; att[tid][l]=e; s+=e; }
    float inv = 1.f/s;
    for (int l=0;l<LL;l++) att[tid][l] *= inv;
  }
  __syncthreads();
  {
    int n2 = tid>>6, h0 = (tid&63)*4;
    float r0=0,r1=0,r2=0,r3=0;
    for (int l=0;l<LL;l++){
      float w = att[n2][l];
      r0 += w*Vl[l][h0]; r1 += w*Vl[l][h0+1]; r2 += w*Vl[l][h0+2]; r3 += w*Vl[l][h0+3];
    }
    float* o = R + (size_t)b*(NSTEPS*HH) + n2*HH + h0;
    o[0]=r0; o[1]=r1; o[2]=r2; o[3]=r3;
  }
}

// prop_sim for ALL steps: psa[s][b][4]
__global__ __launch_bounds__(256) void prop_sim_all_k(const float* __restrict__ R,
                                                      const float* __restrict__ pe,
                                                      float* __restrict__ psa){
  __shared__ float sp[4];
  int gb = blockIdx.x;
  int s = gb >> 8, b = gb & 255;
  int tid = threadIdx.x;
  int p = tid>>6, lane = tid&63;
  const float* instr = R + (size_t)b*(NSTEPS*HH) + s*HH;
  float v = 0.f;
  for (int h=lane; h<HH; h+=64) v += instr[h]*pe[p*HH+h];
  v = wred_sum(v);
  if (lane==0) sp[p] = v;
  __syncthreads();
  if (tid==0){
    float m = fmaxf(fmaxf(sp[0],sp[1]),fmaxf(sp[2],sp[3]));
    float e0=expf(sp[0]-m), e1=expf(sp[1]-m), e2=expf(sp[2]-m), e3=expf(sp[3]-m);
    float ss = e0+e1+e2+e3;
    float* o = psa + (size_t)s*BB*4 + b*4;
    o[0]=e0/ss; o[1]=e1/ss; o[2]=e2/ss; o[3]=e3/ss;
  }
}

// K1: node s_state (wave per node) + edge w[e]-scalar scatter into s_rel (wave per edge)
__global__ __launch_bounds__(256) void nsm_scores_k(
    const __hip_bfloat16* __restrict__ Tf, const __hip_bfloat16* __restrict__ ET,
    const float* __restrict__ R, const float* __restrict__ psa_s,
    const float* __restrict__ W_state, const float* __restrict__ Wr,
    const float* __restrict__ dist, const int* __restrict__ esrc, const int* __restrict__ edst,
    float* __restrict__ s_state, float* __restrict__ s_rel, int step)
{
  const int wave = threadIdx.x >> 6, lane = threadIdx.x & 63;
  const int h0 = lane*4;
  if (blockIdx.x < NN/4){
    int n = blockIdx.x*4 + wave;
    int g = n / NPG;
    const float* instr = R + (size_t)g*(NSTEPS*HH) + step*HH;
    float ps0 = psa_s[g*4], ps1 = psa_s[g*4+1], ps2 = psa_s[g*4+2];
    const unsigned short* t = (const unsigned short*)(Tf + (size_t)n*(3*HH));
    ushort4 t0 = *(const ushort4*)(t + h0);
    ushort4 t1 = *(const ushort4*)(t + HH + h0);
    ushort4 t2 = *(const ushort4*)(t + 2*HH + h0);
    float4 iv = *(const float4*)(instr + h0);
    float4 wv = *(const float4*)(W_state + h0);
    float acc;
    acc  = eluf(iv.x*(ps0*b2f(t0.x)+ps1*b2f(t1.x)+ps2*b2f(t2.x)))*wv.x;
    acc += eluf(iv.y*(ps0*b2f(t0.y)+ps1*b2f(t1.y)+ps2*b2f(t2.y)))*wv.y;
    acc += eluf(iv.z*(ps0*b2f(t0.z)+ps1*b2f(t1.z)+ps2*b2f(t2.z)))*wv.z;
    acc += eluf(iv.w*(ps0*b2f(t0.w)+ps1*b2f(t1.w)+ps2*b2f(t2.w)))*wv.w;
    acc = wred_sum(acc);
    if (lane==0) s_state[n] = acc;
  } else {
    int e = (blockIdx.x - NN/4)*4 + wave;
    int b = e / (NPG*DEG);
    const float* instr = R + (size_t)b*(NSTEPS*HH) + step*HH;
    const unsigned short* et = (const unsigned short*)(ET + (size_t)e*HH);
    ushort4 ev = *(const ushort4*)(et + h0);
    float4 iv = *(const float4*)(instr + h0);
    float4 wv = *(const float4*)(Wr + h0);
    float acc;
    acc  = eluf(iv.x*b2f(ev.x))*wv.x;
    acc += eluf(iv.y*b2f(ev.y))*wv.y;
    acc += eluf(iv.z*b2f(ev.z))*wv.z;
    acc += eluf(iv.w*b2f(ev.w))*wv.w;
    acc = wred_sum(acc);
    if (lane==0) atomicAdd(&s_rel[edst[e]], dist[esrc[e]]*acc);
  }
}

// K2: per-graph — both segment softmaxes + dist update; zeroes s_rel for next step
__global__ __launch_bounds__(256) void nsm_update_k(
    const float* __restrict__ s_state, float* __restrict__ s_rel,
    const float* __restrict__ psa_s, float* __restrict__ dist)
{
  __shared__ float sh[4];
  int b = blockIdx.x, i = threadIdx.x;
  bool ok = (i < NPG);
  float ss = ok ? s_state[b*NPG + i] : -1e30f;
  float sr = ok ? s_rel[b*NPG + i]   : -1e30f;
  float m1 = block_max256(ss, sh);
  float e1 = ok ? expf(ss - m1) : 0.f;
  float d1 = block_sum256(e1, sh);
  float m2 = block_max256(sr, sh);
  float e2 = ok ? expf(sr - m2) : 0.f;
  float d2 = block_sum256(e2, sh);
  if (ok){
    float pst = e1/d1, prl = e2/d2;
    float r = psa_s[b*4+3];
    dist[b*NPG + i] = r*prl + (1.f-r)*pst;
    s_rel[b*NPG + i] = 0.f;
  }
}

__global__ __launch_bounds__(256) void final_agg_k(const float* __restrict__ na, const float* __restrict__ dist,
                                                   const float* __restrict__ ps, float* __restrict__ aggregated){
  int b = blockIdx.x, h = threadIdx.x;
  float ps0 = ps[b*4+0], ps1 = ps[b*4+1], ps2 = ps[b*4+2];
  float acc = 0.f;
  for (int i=0;i<NPG;i++){
    int n = b*NPG + i;
    float d = dist[n];
    const float* a = na + (size_t)n*(3*HH);
    acc += d*(ps0*a[h] + ps1*a[HH+h] + ps2*a[2*HH+h]);
  }
  aggregated[b*HH + h] = acc;
}

__global__ void qa_build_k(const float* __restrict__ Q, const float* __restrict__ aggregated,
                           float* __restrict__ QA){
  int idx = blockIdx.x*256 + threadIdx.x;
  if (idx >= BB*2*HH) return;
  int b = idx >> 9, k = idx & 511;
  QA[idx] = (k < HH) ? Q[b*HH + k] : aggregated[b*HH + (k-HH)];
}

// ---------------- host ----------------
extern "C" void kernel_launch(void* const* d_in, const int* in_sizes, int n_in,
                              void* d_out, int out_size, void* d_ws, size_t ws_size,
                              hipStream_t stream) {
  (void)in_sizes; (void)n_in; (void)out_size; (void)ws_size;
  const float* questions     = (const float*)d_in[0];
  const float* node_attrs    = (const float*)d_in[1];
  const float* edge_attrs    = (const float*)d_in[2];
  const float* vocab         = (const float*)d_in[3];
  const float* default_embed = (const float*)d_in[4];
  const float* W_norm        = (const float*)d_in[5];
  const float* lstm_Wih      = (const float*)d_in[6];   // (1024,256) row-major == Bt
  const float* lstm_Whh      = (const float*)d_in[7];   // (1024,256) row-major == Bt
  const float* lstm_bih      = (const float*)d_in[8];
  const float* lstm_bhh      = (const float*)d_in[9];
  const float* rnn_Wih       = (const float*)d_in[10];  // (256,256) row-major == Bt
  const float* rnn_Whh       = (const float*)d_in[11];
  const float* rnn_bih       = (const float*)d_in[12];
  const float* rnn_bhh       = (const float*)d_in[13];
  const float* prop_embeds   = (const float*)d_in[14];
  const float* Ws_property   = (const float*)d_in[15];
  const float* W_state       = (const float*)d_in[16];
  const float* W_relation    = (const float*)d_in[17];
  const float* lin_W         = (const float*)d_in[18];  // (2000,512) row-major == Bt
  const float* lin_b         = (const float*)d_in[19];
  const int*   lengths       = (const int*)d_in[20];
  const int*   edge_src      = (const int*)d_in[23];
  const int*   edge_dst      = (const int*)d_in[24];
  float* out = (float*)d_out;

  char* base = (char*)d_ws;
  size_t off = 0;
  auto alloc = [&](size_t nbytes)->void*{
    void* p = base + off;
    off += (nbytes + 255) & ~(size_t)255;
    return p;
  };

  __hip_bfloat16* qbf     = (__hip_bfloat16*)alloc((size_t)BL*HH*2);
  __hip_bfloat16* WnT_bf  = (__hip_bfloat16*)alloc((size_t)HH*HH*2);
  __hip_bfloat16* xw_bf   = (__hip_bfloat16*)alloc((size_t)BL*HH*2);
  __hip_bfloat16* Cbv     = (__hip_bfloat16*)alloc((size_t)VPAD*HH*2);
  __hip_bfloat16* vT_bf   = (__hip_bfloat16*)alloc((size_t)HH*KPAD*2);
  __hip_bfloat16* Whh_bf  = (__hip_bfloat16*)alloc((size_t)4*HH*HH*2);
  __hip_bfloat16* rWih_bf = (__hip_bfloat16*)alloc((size_t)HH*HH*2);
  __hip_bfloat16* rWhh_bf = (__hip_bfloat16*)alloc((size_t)HH*HH*2);
  __hip_bfloat16* h_bf    = (__hip_bfloat16*)alloc((size_t)BB*HH*2);
  float* e_def    = (float*)alloc((size_t)BL*4);
  float* row_sum  = (float*)alloc((size_t)BL*4);
  float* Vtag     = (float*)alloc((size_t)BL*HH*4);
  float* bsum     = (float*)alloc((size_t)4*HH*4);
  float* h_buf    = (float*)alloc((size_t)BB*HH*4);
  float* Hins     = (float*)alloc((size_t)BB*NSTEPS*HH*4);
  float* R        = (float*)alloc((size_t)BB*NSTEPS*HH*4);
  float* psa      = (float*)alloc((size_t)NSTEPS*BB*4*4);
  float* s_state  = (float*)alloc((size_t)NN*4);
  float* s_rel    = (float*)alloc((size_t)NN*4);
  float* dist     = (float*)alloc((size_t)NN*4);
  float* aggregated = (float*)alloc((size_t)BB*HH*4);
  float* QA       = (float*)alloc((size_t)BB*2*HH*4);
  __hip_bfloat16* Pm_bf = (__hip_bfloat16*)alloc((size_t)BL*KPAD*2);
  // Tf region (59MB bf16); gX (16.8MB f32) aliases its start (disjoint in time)
  char*  TfR      = (char*)alloc((size_t)NN*3*HH*2);
  __hip_bfloat16* Tf = (__hip_bfloat16*)TfR;
  float* gX          = (float*)TfR;
  __hip_bfloat16* ET = (__hip_bfloat16*)alloc((size_t)EE*HH*2);

  // ---- setup ----
  init_k<<<(NN+255)/256, 256, 0, stream>>>(dist, s_rel);
  cvt_bf16_k<<<(BL*HH/4+255)/256, 256, 0, stream>>>(questions, qbf, BL*HH);
  tr_cvt_k<<<(HH*HH+255)/256, 256, 0, stream>>>(W_norm, WnT_bf, HH, HH);
  build_cb_k<<<(VPAD*HH+255)/256, 256, 0, stream>>>(vocab, default_embed, Cbv);
  build_vt_k<<<(HH*KPAD+255)/256, 256, 0, stream>>>(vocab, vT_bf);
  cvt_bf16_k<<<(4*HH*HH/4+255)/256, 256, 0, stream>>>(lstm_Whh, Whh_bf, 4*HH*HH);
  cvt_bf16_k<<<(HH*HH/4+255)/256, 256, 0, stream>>>(rnn_Wih, rWih_bf, HH*HH);
  cvt_bf16_k<<<(HH*HH/4+255)/256, 256, 0, stream>>>(rnn_Whh, rWhh_bf, HH*HH);
  bsum_k<<<(4*HH+255)/256, 256, 0, stream>>>(lstm_bih, lstm_bhh, bsum);
  zero_k<<<(BL+255)/256, 256, 0, stream>>>(row_sum, BL);
  zero_k<<<(BL*HH+255)/256, 256, 0, stream>>>(Vtag, BL*HH);

  // ---- phase A: word embedding ----
  mfma_bt_bf16_k<1><<<dim3(2,32,1), 256, 0, stream>>>(qbf, WnT_bf, nullptr, xw_bf,
      HH, HH, HH, HH, HH/32, HH/32, nullptr, nullptr);
  gemm_exp_k<<<dim3(VPAD/128, BL/128, 1), 256, 0, stream>>>(xw_bf, Cbv, Pm_bf, row_sum, e_def);
  inv_k<<<(BL+255)/256, 256, 0, stream>>>(row_sum, BL);
  mfma_bt_bf16_k<2><<<dim3(HH/128, BL/128, 8), 256, 0, stream>>>(
      Pm_bf, vT_bf, Vtag, nullptr, KPAD, KPAD, HH, HH, KPAD/32, 20, nullptr, row_sum);
  vtag_epi_k<<<BL, HH, 0, stream>>>(Vtag, e_def, row_sum, questions);

  // ---- phase B: LSTM encoder ----
  mfma_bt_f32_k<0><<<dim3(8,32,1), 256, 0, stream>>>(Vtag, lstm_Wih, gX, nullptr,
      HH, HH, 4*HH, 4*HH, HH/32, bsum);
  lstm_persist_k<<<16, 1024, 0, stream>>>(gX, Whh_bf, lengths, h_buf, h_bf);

  // ---- phase C: decoder RNN ----
  dec_persist_k<<<16, 1024, 0, stream>>>(h_bf, rWih_bf, rWhh_bf, rnn_bih, rnn_bhh, Hins);

  // ---- phase D: attention -> R; prop_sim for all steps ----
  attention_k<<<BB, 256, 0, stream>>>(Vtag, Hins, lengths, R);
  prop_sim_all_k<<<NSTEPS*BB, 256, 0, stream>>>(R, prop_embeds, psa);

  // ---- phase E: step-invariant heavy GEMMs (bf16 out). Clobbers gX (dead). ----
  for (int p=0; p<3; p++)
    mfma_bt_f32_k<1><<<dim3(2,NN/128,1), 256, 0, stream>>>(
        node_attrs + (size_t)p*HH, Ws_property + (size_t)p*HH*HH,
        nullptr, Tf + (size_t)p*HH, 3*HH, HH, 3*HH, HH, HH/32, nullptr);
  mfma_bt_f32_k<1><<<dim3(2,EE/128,1), 256, 0, stream>>>(
      edge_attrs, Ws_property + (size_t)3*HH*HH,
      nullptr, ET, HH, HH, HH, HH, HH/32, nullptr);

  // ---- phase F: 4-step NSM loop ----
  for (int s=0; s<NSTEPS; s++){
    const float* psa_s = psa + (size_t)s*BB*4;
    nsm_scores_k<<<NN/4 + EE/4, 256, 0, stream>>>(
        Tf, ET, R, psa_s, W_state, W_relation, dist, edge_src, edge_dst,
        s_state, s_rel, s);
    nsm_update_k<<<BB, 256, 0, stream>>>(s_state, s_rel, psa_s, dist);
  }

  // ---- phase G: readout ----
  final_agg_k<<<BB, 256, 0, stream>>>(node_attrs, dist, psa + (size_t)3*BB*4, aggregated);
  qa_build_k<<<(BB*2*HH+255)/256, 256, 0, stream>>>(h_buf, aggregated, QA);
  mfma_bt_f32_k<0><<<dim3(16,2,1), 256, 0, stream>>>(QA, lin_W, out, nullptr,
      2*HH, 2*HH, OUTD, OUTD, 2*HH/32, lin_b);
}

// Round 3
// 1001.345 us; speedup vs baseline: 1.2427x; 1.0986x over previous
//
#include <hip/hip_runtime.h>
#include <hip/hip_bf16.h>
#include <math.h>

// Problem constants
#define BB 256
#define LL 16
#define HH 256
#define VV 5000
#define NPG 150
#define DEG 4
#define NSTEPS 4
#define OUTD 2000
#define NN (BB*NPG)      // 38400
#define EE (BB*NPG*DEG)  // 153600
#define BL (BB*LL)       // 4096
#define VPAD 5120        // logits column pad (40*128)
#define KPAD 5024        // Pm K pad (157*32)

// ---------------- helpers ----------------
__device__ __forceinline__ float wred_sum(float v){
  #pragma unroll
  for(int o=32;o;o>>=1) v += __shfl_down(v,o,64);
  return v;
}
__device__ __forceinline__ float wred_max(float v){
  #pragma unroll
  for(int o=32;o;o>>=1) v = fmaxf(v,__shfl_down(v,o,64));
  return v;
}
__device__ __forceinline__ float block_sum256(float v, float* sh){
  v = wred_sum(v);
  __syncthreads();
  if((threadIdx.x&63)==0) sh[threadIdx.x>>6]=v;
  __syncthreads();
  return sh[0]+sh[1]+sh[2]+sh[3];
}
__device__ __forceinline__ float block_max256(float v, float* sh){
  v = wred_max(v);
  __syncthreads();
  if((threadIdx.x&63)==0) sh[threadIdx.x>>6]=v;
  __syncthreads();
  return fmaxf(fmaxf(sh[0],sh[1]),fmaxf(sh[2],sh[3]));
}
__device__ __forceinline__ float eluf(float x){ return x>0.f ? x : expm1f(x); }
__device__ __forceinline__ float sigf(float x){ return 1.f/(1.f+expf(-x)); }
// fast saturating sigmoid/tanh (v_exp + v_rcp; ~1e-7 rel err, exact limits)
__device__ __forceinline__ float fsig(float x){
  return __builtin_amdgcn_rcpf(1.f + __expf(-x));
}
__device__ __forceinline__ float ftanh(float x){
  return 1.f - 2.f*__builtin_amdgcn_rcpf(1.f + __expf(2.f*x));
}
__device__ __forceinline__ float b2f(unsigned short s){
  union{float f; unsigned int u;} x; x.u = ((unsigned int)s)<<16; return x.f;
}
__device__ __forceinline__ unsigned short f2bf_bits(float x){
  union { __hip_bfloat16 h; unsigned short s; } u; u.h = __float2bfloat16(x); return u.s;
}

// async global->LDS 16B (gfx950), lds dest = wave-uniform base + lane*16
__device__ __forceinline__ void async16(void* lds, const void* g){
  __builtin_amdgcn_global_load_lds(
      (const __attribute__((address_space(1))) unsigned int*)g,
      (__attribute__((address_space(3))) unsigned int*)lds, 16, 0, 0);
}

typedef __attribute__((ext_vector_type(8))) short short8;
typedef __attribute__((ext_vector_type(4))) float f32x4;

__device__ __forceinline__ short8 pack8(float4 a, float4 b){
  short8 r;
  r[0]=(short)f2bf_bits(a.x); r[1]=(short)f2bf_bits(a.y);
  r[2]=(short)f2bf_bits(a.z); r[3]=(short)f2bf_bits(a.w);
  r[4]=(short)f2bf_bits(b.x); r[5]=(short)f2bf_bits(b.y);
  r[6]=(short)f2bf_bits(b.z); r[7]=(short)f2bf_bits(b.w);
  return r;
}

// =======================================================================
// MFMA GEMM, C[m,n] = sum_k A[m,k]*Bt[n,k].  128x128 tile, BK=32, 4 waves.
// EPI: 0 = f32 store (+bias, col<Nreal), 1 = bf16 store, 2 = f32 atomicAdd
//      (EPI 2: optional per-row scale rscale[row])
// =======================================================================
template<int EPI>
__global__ __launch_bounds__(256) void mfma_bt_bf16_k(
    const __hip_bfloat16* __restrict__ A, const __hip_bfloat16* __restrict__ Bt,
    float* __restrict__ Cf, __hip_bfloat16* __restrict__ Cb,
    int lda, int ldb, int ldc, int Nreal,
    int kItersTotal, int kPerSplit, const float* __restrict__ bias,
    const float* __restrict__ rscale)
{
  __shared__ __hip_bfloat16 As[128*32];
  __shared__ __hip_bfloat16 Bs[128*32];
  const int bm = blockIdx.y*128, bn = blockIdx.x*128;
  const int tid = threadIdx.x;
  int k0 = blockIdx.z * kPerSplit;
  int k1 = k0 + kPerSplit; if (k1 > kItersTotal) k1 = kItersTotal;
  const int lane = tid & 63, wave = tid >> 6;
  const int quad = lane >> 4, r16 = lane & 15;
  const int wr = wave >> 1, wc = wave & 1;
  f32x4 acc[4][4] = {};
  const int c0 = tid, c1 = tid + 256;
  const int ar0 = c0 >> 2, ak0 = (c0 & 3)*8;
  const int ar1 = c1 >> 2, ak1 = (c1 & 3)*8;
  const __hip_bfloat16* Ab = A + (size_t)bm*lda;
  const __hip_bfloat16* Bb = Bt + (size_t)bn*ldb;
  for (int kk = k0; kk < k1; ++kk){
    const int kb = kk*32;
    async16(&As[c0*8], Ab + (size_t)ar0*lda + kb + ak0);
    async16(&As[c1*8], Ab + (size_t)ar1*lda + kb + ak1);
    async16(&Bs[c0*8], Bb + (size_t)ar0*ldb + kb + ak0);
    async16(&Bs[c1*8], Bb + (size_t)ar1*ldb + kb + ak1);
    __syncthreads();
    short8 av[4], bv[4];
    #pragma unroll
    for (int i=0;i<4;i++){
      av[i] = *(const short8*)&As[(wr*64 + i*16 + r16)*32 + quad*8];
      bv[i] = *(const short8*)&Bs[(wc*64 + i*16 + r16)*32 + quad*8];
    }
    #pragma unroll
    for (int i=0;i<4;i++)
      #pragma unroll
      for (int j=0;j<4;j++)
        acc[i][j] = __builtin_amdgcn_mfma_f32_16x16x32_bf16(av[i], bv[j], acc[i][j], 0,0,0);
    __syncthreads();
  }
  #pragma unroll
  for (int i=0;i<4;i++){
    int row = bm + wr*64 + i*16 + quad*4;
    #pragma unroll
    for (int j=0;j<4;j++){
      int col = bn + wc*64 + j*16 + r16;
      if (col >= Nreal) continue;
      #pragma unroll
      for (int r=0;r<4;r++){
        float v = acc[i][j][r];
        if (EPI==0){ if (bias) v += bias[col]; Cf[(size_t)(row+r)*ldc + col] = v; }
        else if (EPI==1){ Cb[(size_t)(row+r)*ldc + col] = __float2bfloat16(v); }
        else { if (rscale) v *= rscale[row+r]; atomicAdd(&Cf[(size_t)(row+r)*ldc + col], v); }
      }
    }
  }
}

// Same GEMM, f32 global operands, packed bf16 staging (2x float4 -> 1x b128 LDS write)
template<int EPI>
__global__ __launch_bounds__(256) void mfma_bt_f32_k(
    const float* __restrict__ A, const float* __restrict__ Bt,
    float* __restrict__ Cf, __hip_bfloat16* __restrict__ Cb,
    int lda, int ldb, int ldc, int Nreal,
    int kIters, const float* __restrict__ bias)
{
  __shared__ __hip_bfloat16 As[128*32];
  __shared__ __hip_bfloat16 Bs[128*32];
  const int bm = blockIdx.y*128, bn = blockIdx.x*128;
  const int tid = threadIdx.x;
  const int lane = tid & 63, wave = tid >> 6;
  const int quad = lane >> 4, r16 = lane & 15;
  const int wr = wave >> 1, wc = wave & 1;
  f32x4 acc[4][4] = {};
  for (int kk = 0; kk < kIters; ++kk){
    const int kb = kk*32;
    #pragma unroll
    for (int i=0;i<2;i++){
      int c = tid + i*256;
      int row = c >> 2, k0 = (c & 3)*8;
      const float* src = A + (size_t)(bm+row)*lda + kb + k0;
      float4 v0 = *(const float4*)(src);
      float4 v1 = *(const float4*)(src+4);
      *(short8*)&As[row*32 + k0] = pack8(v0, v1);
    }
    #pragma unroll
    for (int i=0;i<2;i++){
      int c = tid + i*256;
      int row = c >> 2, k0 = (c & 3)*8;
      float4 v0 = {0.f,0.f,0.f,0.f}, v1 = {0.f,0.f,0.f,0.f};
      if (bn + row < Nreal){
        const float* src = Bt + (size_t)(bn+row)*ldb + kb + k0;
        v0 = *(const float4*)(src);
        v1 = *(const float4*)(src+4);
      }
      *(short8*)&Bs[row*32 + k0] = pack8(v0, v1);
    }
    __syncthreads();
    short8 av[4], bv[4];
    #pragma unroll
    for (int i=0;i<4;i++){
      av[i] = *(const short8*)&As[(wr*64 + i*16 + r16)*32 + quad*8];
      bv[i] = *(const short8*)&Bs[(wc*64 + i*16 + r16)*32 + quad*8];
    }
    #pragma unroll
    for (int i=0;i<4;i++)
      #pragma unroll
      for (int j=0;j<4;j++)
        acc[i][j] = __builtin_amdgcn_mfma_f32_16x16x32_bf16(av[i], bv[j], acc[i][j], 0,0,0);
    __syncthreads();
  }
  #pragma unroll
  for (int i=0;i<4;i++){
    int row = bm + wr*64 + i*16 + quad*4;
    #pragma unroll
    for (int j=0;j<4;j++){
      int col = bn + wc*64 + j*16 + r16;
      if (col >= Nreal) continue;
      #pragma unroll
      for (int r=0;r<4;r++){
        float v = acc[i][j][r];
        if (EPI==0){ if (bias) v += bias[col]; Cf[(size_t)(row+r)*ldc + col] = v; }
        else { Cb[(size_t)(row+r)*ldc + col] = __float2bfloat16(v); }
      }
    }
  }
}

// Fused logits GEMM + exp epilogue: Pm[r][c] = exp(logit) (unnormalized, bf16),
// row_sum[r] += partial sums (cols 0..VV), e_def[r] = exp(logit[VV]).
__global__ __launch_bounds__(256) void gemm_exp_k(
    const __hip_bfloat16* __restrict__ A, const __hip_bfloat16* __restrict__ Bt,
    __hip_bfloat16* __restrict__ Pm, float* __restrict__ row_sum,
    float* __restrict__ e_def)
{
  __shared__ __hip_bfloat16 As[128*32];
  __shared__ __hip_bfloat16 Bs[128*32];
  const int bm = blockIdx.y*128, bn = blockIdx.x*128;
  const int tid = threadIdx.x;
  const int lane = tid & 63, wave = tid >> 6;
  const int quad = lane >> 4, r16 = lane & 15;
  const int wr = wave >> 1, wc = wave & 1;
  f32x4 acc[4][4] = {};
  const int c0 = tid, c1 = tid + 256;
  const int ar0 = c0 >> 2, ak0 = (c0 & 3)*8;
  const int ar1 = c1 >> 2, ak1 = (c1 & 3)*8;
  const __hip_bfloat16* Ab = A + (size_t)bm*HH;
  const __hip_bfloat16* Bb = Bt + (size_t)bn*HH;
  for (int kk = 0; kk < HH/32; ++kk){
    const int kb = kk*32;
    async16(&As[c0*8], Ab + (size_t)ar0*HH + kb + ak0);
    async16(&As[c1*8], Ab + (size_t)ar1*HH + kb + ak1);
    async16(&Bs[c0*8], Bb + (size_t)ar0*HH + kb + ak0);
    async16(&Bs[c1*8], Bb + (size_t)ar1*HH + kb + ak1);
    __syncthreads();
    short8 av[4], bv[4];
    #pragma unroll
    for (int i=0;i<4;i++){
      av[i] = *(const short8*)&As[(wr*64 + i*16 + r16)*32 + quad*8];
      bv[i] = *(const short8*)&Bs[(wc*64 + i*16 + r16)*32 + quad*8];
    }
    #pragma unroll
    for (int i=0;i<4;i++)
      #pragma unroll
      for (int j=0;j<4;j++)
        acc[i][j] = __builtin_amdgcn_mfma_f32_16x16x32_bf16(av[i], bv[j], acc[i][j], 0,0,0);
    __syncthreads();
  }
  #pragma unroll
  for (int i=0;i<4;i++){
    int rowb = bm + wr*64 + i*16 + quad*4;
    float rsum[4] = {0.f,0.f,0.f,0.f};
    #pragma unroll
    for (int j=0;j<4;j++){
      int col = bn + wc*64 + j*16 + r16;
      #pragma unroll
      for (int r=0;r<4;r++){
        float e = (col <= VV) ? expf(acc[i][j][r]) : 0.f;
        rsum[r] += e;
        if (col < KPAD) Pm[(size_t)(rowb+r)*KPAD + col] = __float2bfloat16(col < VV ? e : 0.f);
        if (col == VV) e_def[rowb+r] = e;
      }
    }
    #pragma unroll
    for (int r=0;r<4;r++){
      float s = rsum[r];
      s += __shfl_xor(s, 1, 64);
      s += __shfl_xor(s, 2, 64);
      s += __shfl_xor(s, 4, 64);
      s += __shfl_xor(s, 8, 64);
      if (r16 == 0) atomicAdd(&row_sum[rowb+r], s);
    }
  }
}

// =======================================================================
// Persistent batch-parallel LSTM, v4: 16 blocks x 1024 threads (16 waves).
// __launch_bounds__(1024, 4): 4 waves/EU -> 128 VGPR cap (v3's implicit
// 64-VGPR cap serialized all memory; VGPR_Count was 64).
// Weight placement per wave (4 gate-blocks of 16 rows, K=256 cols):
//   - kc 0..3 (cols 0..127):   registers, ALL waves (16 short8 = 64 VGPR)
//   - kc 4..7 (cols 128..255): LDS Wl for waves 0..7 (512 rows x 132 stride)
//   - kc 4..7 waves 8..15:     streamed from L2 each step (16KB/wave/step,
//                              now pipelinable with the VGPR headroom)
// gx loads hoisted to top of step; fast saturating sig/tanh.
// =======================================================================
__global__ __launch_bounds__(1024, 4) void lstm_persist_k(
    const float* __restrict__ gX, const __hip_bfloat16* __restrict__ Whh_bf,
    const int* __restrict__ lengths,
    float* __restrict__ h_out, __hip_bfloat16* __restrict__ hbf_out)
{
  __shared__ __hip_bfloat16 Wl[512*132];      // kc4..7, waves 0..7 (135.2KB)
  __shared__ __hip_bfloat16 hbuf[2][16*264];  // double-buffered recurrent h
  const int bg = blockIdx.x, tid = threadIdx.x;
  const int lane = tid & 63, w = tid >> 6;
  const int quad = lane >> 4, r16 = lane & 15;
  const int hb = w*16;
  // preload Wl: row = ww*64 + g*16 + rr  <->  Whh row g*256 + ww*16 + rr, cols 128..255
  for (int idx = tid; idx < 512*16; idx += 1024){
    int row = idx >> 4, c8 = (idx & 15)*8;
    int ww = row >> 6, g = (row >> 4) & 3, rr = row & 15;
    *(short8*)&Wl[row*132 + c8] =
        *(const short8*)&Whh_bf[((size_t)(g*256 + ww*16 + rr))*256 + 128 + c8];
  }
  // register-resident weights: kc 0..3, all waves (64 VGPR)
  short8 rW[4][4];
  #pragma unroll
  for (int kc=0; kc<4; kc++)
    #pragma unroll
    for (int g=0; g<4; g++)
      rW[kc][g] = *(const short8*)&Whh_bf[((size_t)(g*256 + hb + r16))*256 + kc*32 + quad*8];
  for (int i = tid; i < 16*264; i += 1024) hbuf[0][i] = __float2bfloat16(0.f);
  int lenr[4];
  #pragma unroll
  for (int r=0;r<4;r++) lenr[r] = lengths[bg*16 + quad*4 + r];
  __syncthreads();
  f32x4 cstate = {0.f,0.f,0.f,0.f};
  f32x4 hstate = {0.f,0.f,0.f,0.f};
  int p = 0;
  const float* gXb = gX + (size_t)bg*16*LL*(4*HH) + hb + r16;
  for (int t=0; t<LL; t++){
    // gx prefetch (independent of h_{t-1}; in flight across the MFMA phase)
    float gxv[4][4];
    #pragma unroll
    for (int r=0;r<4;r++)
      #pragma unroll
      for (int g=0;g<4;g++)
        gxv[r][g] = gXb[((size_t)((quad*4+r)*LL + t))*(4*HH) + g*HH];
    f32x4 acc[4] = {};
    const __hip_bfloat16* hr = hbuf[p];
    #pragma unroll
    for (int kc=0; kc<4; kc++){
      short8 a = *(const short8*)&hr[r16*264 + kc*32 + quad*8];
      #pragma unroll
      for (int g=0; g<4; g++)
        acc[g] = __builtin_amdgcn_mfma_f32_16x16x32_bf16(a, rW[kc][g], acc[g], 0,0,0);
    }
    if (w < 8){
      #pragma unroll
      for (int kc=4; kc<8; kc++){
        short8 a = *(const short8*)&hr[r16*264 + kc*32 + quad*8];
        #pragma unroll
        for (int g=0; g<4; g++){
          short8 b = *(const short8*)&Wl[(w*64 + g*16 + r16)*132 + (kc-4)*32 + quad*8];
          acc[g] = __builtin_amdgcn_mfma_f32_16x16x32_bf16(a, b, acc[g], 0,0,0);
        }
      }
    } else {
      #pragma unroll
      for (int kc=4; kc<8; kc++){
        short8 a = *(const short8*)&hr[r16*264 + kc*32 + quad*8];
        #pragma unroll
        for (int g=0; g<4; g++){
          short8 b = *(const short8*)&Whh_bf[((size_t)(g*256 + hb + r16))*256 + kc*32 + quad*8];
          acc[g] = __builtin_amdgcn_mfma_f32_16x16x32_bf16(a, b, acc[g], 0,0,0);
        }
      }
    }
    #pragma unroll
    for (int r=0;r<4;r++){
      int batch = quad*4 + r;
      float gi = acc[0][r] + gxv[r][0];
      float gf = acc[1][r] + gxv[r][1];
      float gc = acc[2][r] + gxv[r][2];
      float go = acc[3][r] + gxv[r][3];
      float cn = fsig(gf)*cstate[r] + fsig(gi)*ftanh(gc);
      float hn = fsig(go)*ftanh(cn);
      if (t < lenr[r]){ cstate[r] = cn; hstate[r] = hn; }
      hbuf[p^1][batch*264 + hb + r16] = __float2bfloat16(hstate[r]);
    }
    p ^= 1;
    __syncthreads();
  }
  #pragma unroll
  for (int r=0;r<4;r++){
    int batch = quad*4 + r;
    size_t o = (size_t)(bg*16+batch)*HH + hb + r16;
    h_out[o] = hstate[r];
    hbf_out[o] = __float2bfloat16(hstate[r]);
  }
}

// Persistent batch-parallel decoder RNN: 16 blocks x 1024 threads.
// Entire Whh (128KB) cached in LDS; qp and x-state in registers; step 0 has
// h=0 so its MFMA is skipped entirely. (1024,4) -> 128 VGPR cap.
__global__ __launch_bounds__(1024, 4) void dec_persist_k(
    const __hip_bfloat16* __restrict__ Qbf, const __hip_bfloat16* __restrict__ Wih_bf,
    const __hip_bfloat16* __restrict__ Whh_bf,
    const float* __restrict__ bih, const float* __restrict__ bhh,
    float* __restrict__ Hins)
{
  __shared__ __hip_bfloat16 Wl[256*264];     // full Whh, 132KB
  __shared__ __hip_bfloat16 xb[2][16*264];
  const int bg = blockIdx.x, tid = threadIdx.x;
  const int lane = tid & 63, w = tid >> 6;
  const int quad = lane >> 4, r16 = lane & 15;
  const int col = w*16 + r16;
  for (int c = tid; c < 8192; c += 1024){
    int row = c >> 5, ci = (c & 31)*8;
    *(short8*)&Wl[row*264 + ci] = *(const short8*)&Whh_bf[(size_t)row*256 + ci];
  }
  // qp = Q @ Wih^T  (A rows straight from global; Wih streamed from L2 once)
  f32x4 qp = {};
  #pragma unroll
  for (int kc=0; kc<8; kc++){
    short8 a = *(const short8*)&Qbf[(size_t)(bg*16 + r16)*HH + kc*32 + quad*8];
    short8 b = *(const short8*)&Wih_bf[(size_t)col*HH + kc*32 + quad*8];
    qp = __builtin_amdgcn_mfma_f32_16x16x32_bf16(a, b, qp, 0,0,0);
  }
  const float bihv = bih[col], bhhv = bhh[col];
  __syncthreads();           // Wl ready
  // s = 0: hx=0 -> x = relu(qp + bih + bhh)
  #pragma unroll
  for (int r=0;r<4;r++){
    int batch = quad*4 + r;
    float v = fmaxf(qp[r] + bihv + bhhv, 0.f);
    xb[0][batch*264 + col] = __float2bfloat16(v);
    Hins[(size_t)(bg*16+batch)*(NSTEPS*HH) + 0*HH + col] = v;
  }
  __syncthreads();
  int p = 0;
  for (int s=1; s<NSTEPS; s++){
    f32x4 acc = {};
    #pragma unroll
    for (int kc=0; kc<8; kc++){
      short8 a = *(const short8*)&xb[p][r16*264 + kc*32 + quad*8];
      short8 b = *(const short8*)&Wl[col*264 + kc*32 + quad*8];
      acc = __builtin_amdgcn_mfma_f32_16x16x32_bf16(a, b, acc, 0,0,0);
    }
    #pragma unroll
    for (int r=0;r<4;r++){
      int batch = quad*4 + r;
      float v = fmaxf(qp[r] + bihv + acc[r] + bhhv, 0.f);
      xb[p^1][batch*264 + col] = __float2bfloat16(v);
      Hins[(size_t)(bg*16+batch)*(NSTEPS*HH) + s*HH + col] = v;
    }
    p ^= 1;
    __syncthreads();
  }
}

// ---------------- small utility kernels ----------------
__global__ void cvt_bf16_k(const float* __restrict__ src, __hip_bfloat16* __restrict__ dst, int n){
  int i = (blockIdx.x*256 + threadIdx.x)*4;
  if (i >= n) return;
  float4 v = *(const float4*)(src + i);
  dst[i]   = __float2bfloat16(v.x);
  dst[i+1] = __float2bfloat16(v.y);
  dst[i+2] = __float2bfloat16(v.z);
  dst[i+3] = __float2bfloat16(v.w);
}

__global__ void tr_cvt_k(const float* __restrict__ src, __hip_bfloat16* __restrict__ dst, int R, int Ccols){
  int idx = blockIdx.x*256 + threadIdx.x;
  if (idx >= R*Ccols) return;
  int r = idx / Ccols, c = idx % Ccols;
  dst[(size_t)c*R + r] = __float2bfloat16(src[idx]);
}

__global__ void build_cb_k(const float* __restrict__ vocab, const float* __restrict__ de,
                           __hip_bfloat16* __restrict__ Cb){
  int idx = blockIdx.x*256 + threadIdx.x;
  if (idx >= VPAD*HH) return;
  int v = idx >> 8, h = idx & 255;
  float x = (v < VV) ? vocab[(size_t)v*HH + h] : (v == VV ? de[h] : 0.f);
  Cb[idx] = __float2bfloat16(x);
}

__global__ void build_vt_k(const float* __restrict__ vocab, __hip_bfloat16* __restrict__ VT){
  int idx = blockIdx.x*256 + threadIdx.x;
  if (idx >= HH*KPAD) return;
  int h = idx / KPAD, v = idx % KPAD;
  VT[idx] = __float2bfloat16(v < VV ? vocab[(size_t)v*HH + h] : 0.f);
}

__global__ void bsum_k(const float* a, const float* b, float* o){
  int i = blockIdx.x*256 + threadIdx.x;
  if (i < 4*HH) o[i] = a[i] + b[i];
}

__global__ void init_k(float* dist, float* s_rel){
  int idx = blockIdx.x*256 + threadIdx.x;
  if (idx < NN){ dist[idx] = 1.f/150.f; s_rel[idx] = 0.f; }
}

__global__ void zero_k(float* p, int n){
  int idx = blockIdx.x*256 + threadIdx.x;
  if (idx < n) p[idx] = 0.f;
}

__global__ void inv_k(float* p, int n){
  int idx = blockIdx.x*256 + threadIdx.x;
  if (idx < n) p[idx] = 1.f/p[idx];
}

__global__ void vtag_epi_k(float* __restrict__ Vtag, const float* __restrict__ e_def,
                           const float* __restrict__ inv_s, const float* __restrict__ words){
  int r = blockIdx.x, h = threadIdx.x;
  size_t o = (size_t)r*HH + h;
  Vtag[o] += e_def[r]*inv_s[r]*words[o];
}

// attention per graph
__global__ __launch_bounds__(256) void attention_k(const float* __restrict__ Vtag,
                                                   const float* __restrict__ Hins,
                                                   const int* __restrict__ lengths,
                                                   float* __restrict__ R){
  __shared__ float Vl[LL][HH];
  __shared__ float Hn[NSTEPS][HH];
  __shared__ float att[NSTEPS][LL];
  int b = blockIdx.x, tid = threadIdx.x;
  for (int idx=tid; idx<LL*HH; idx+=256){ int l=idx>>8, h=idx&255; Vl[l][h] = Vtag[((size_t)b*LL+l)*HH + h]; }
  for (int idx=tid; idx<NSTEPS*HH; idx+=256){ Hn[idx>>8][idx&255] = Hins[(size_t)b*(NSTEPS*HH) + idx]; }
  __syncthreads();
  if (tid < NSTEPS*LL){
    int n2 = tid>>4, l = tid&15;
    float s = 0.f;
    for (int k=0;k<HH;k++) s += Hn[n2][k]*Vl[l][k];
    att[n2][l] = s;
  }
  __syncthreads();
  int len = lengths[b];
  if (tid < NSTEPS){
    float m = -1e30f;
    for (int l=0;l<len;l++) m = fmaxf(m, att[tid][l]);
    float s = 0.f;
    for (int l=0;l<LL;l++){ float e = (l<len)? expf(att[tid][l]-m) : 0.f; att[tid][l]=e; s+=e; }
    float inv = 1.f/s;
    for (int l=0;l<LL;l++) att[tid][l] *= inv;
  }
  __syncthreads();
  {
    int n2 = tid>>6, h0 = (tid&63)*4;
    float r0=0,r1=0,r2=0,r3=0;
    for (int l=0;l<LL;l++){
      float w = att[n2][l];
      r0 += w*Vl[l][h0]; r1 += w*Vl[l][h0+1]; r2 += w*Vl[l][h0+2]; r3 += w*Vl[l][h0+3];
    }
    float* o = R + (size_t)b*(NSTEPS*HH) + n2*HH + h0;
    o[0]=r0; o[1]=r1; o[2]=r2; o[3]=r3;
  }
}

// prop_sim for ALL steps: psa[s][b][4]
__global__ __launch_bounds__(256) void prop_sim_all_k(const float* __restrict__ R,
                                                      const float* __restrict__ pe,
                                                      float* __restrict__ psa){
  __shared__ float sp[4];
  int gb = blockIdx.x;
  int s = gb >> 8, b = gb & 255;
  int tid = threadIdx.x;
  int p = tid>>6, lane = tid&63;
  const float* instr = R + (size_t)b*(NSTEPS*HH) + s*HH;
  float v = 0.f;
  for (int h=lane; h<HH; h+=64) v += instr[h]*pe[p*HH+h];
  v = wred_sum(v);
  if (lane==0) sp[p] = v;
  __syncthreads();
  if (tid==0){
    float m = fmaxf(fmaxf(sp[0],sp[1]),fmaxf(sp[2],sp[3]));
    float e0=expf(sp[0]-m), e1=expf(sp[1]-m), e2=expf(sp[2]-m), e3=expf(sp[3]-m);
    float ss = e0+e1+e2+e3;
    float* o = psa + (size_t)s*BB*4 + b*4;
    o[0]=e0/ss; o[1]=e1/ss; o[2]=e2/ss; o[3]=e3/ss;
  }
}

// ONE pass over Tf/ET computing ALL 4 steps' reductions (node scores and
// edge scalars). Step-dependence enters only through instr/psa, NOT dist,
// so the 137MB of Tf+ET is read once instead of 4x.
__global__ __launch_bounds__(256) void nsm_all_k(
    const __hip_bfloat16* __restrict__ Tf, const __hip_bfloat16* __restrict__ ET,
    const float* __restrict__ R, const float* __restrict__ psa,
    const float* __restrict__ W_state, const float* __restrict__ Wr,
    float* __restrict__ s_state_all, float* __restrict__ acc_e_all)
{
  const int wave = threadIdx.x >> 6, lane = threadIdx.x & 63;
  const int h0 = lane*4;
  if (blockIdx.x < NN/4){
    int n = blockIdx.x*4 + wave;
    int g = n / NPG;
    const unsigned short* t = (const unsigned short*)(Tf + (size_t)n*(3*HH));
    ushort4 t0 = *(const ushort4*)(t + h0);
    ushort4 t1 = *(const ushort4*)(t + HH + h0);
    ushort4 t2 = *(const ushort4*)(t + 2*HH + h0);
    float4 wv = *(const float4*)(W_state + h0);
    #pragma unroll
    for (int s=0; s<NSTEPS; s++){
      const float* instr = R + (size_t)g*(NSTEPS*HH) + s*HH;
      const float* ps = psa + (size_t)s*BB*4 + g*4;
      float ps0 = ps[0], ps1 = ps[1], ps2 = ps[2];
      float4 iv = *(const float4*)(instr + h0);
      float acc;
      acc  = eluf(iv.x*(ps0*b2f(t0.x)+ps1*b2f(t1.x)+ps2*b2f(t2.x)))*wv.x;
      acc += eluf(iv.y*(ps0*b2f(t0.y)+ps1*b2f(t1.y)+ps2*b2f(t2.y)))*wv.y;
      acc += eluf(iv.z*(ps0*b2f(t0.z)+ps1*b2f(t1.z)+ps2*b2f(t2.z)))*wv.z;
      acc += eluf(iv.w*(ps0*b2f(t0.w)+ps1*b2f(t1.w)+ps2*b2f(t2.w)))*wv.w;
      acc = wred_sum(acc);
      if (lane==0) s_state_all[(size_t)s*NN + n] = acc;
    }
  } else {
    int e = (blockIdx.x - NN/4)*4 + wave;
    int b = e / (NPG*DEG);
    const unsigned short* et = (const unsigned short*)(ET + (size_t)e*HH);
    ushort4 ev = *(const ushort4*)(et + h0);
    float4 wv = *(const float4*)(Wr + h0);
    #pragma unroll
    for (int s=0; s<NSTEPS; s++){
      const float* instr = R + (size_t)b*(NSTEPS*HH) + s*HH;
      float4 iv = *(const float4*)(instr + h0);
      float acc;
      acc  = eluf(iv.x*b2f(ev.x))*wv.x;
      acc += eluf(iv.y*b2f(ev.y))*wv.y;
      acc += eluf(iv.z*b2f(ev.z))*wv.z;
      acc += eluf(iv.w*b2f(ev.w))*wv.w;
      acc = wred_sum(acc);
      if (lane==0) acc_e_all[(size_t)s*EE + e] = acc;
    }
  }
}

// per-step edge scatter: s_rel[edst[e]] += dist[esrc[e]] * acc_e[e]
__global__ void rel_scatter_k(const float* __restrict__ acc_e, const float* __restrict__ dist,
                              const int* __restrict__ esrc, const int* __restrict__ edst,
                              float* __restrict__ s_rel){
  int e = blockIdx.x*256 + threadIdx.x;
  if (e < EE) atomicAdd(&s_rel[edst[e]], dist[esrc[e]]*acc_e[e]);
}

// K2: per-graph — both segment softmaxes + dist update; zeroes s_rel for next step
__global__ __launch_bounds__(256) void nsm_update_k(
    const float* __restrict__ s_state, float* __restrict__ s_rel,
    const float* __restrict__ psa_s, float* __restrict__ dist)
{
  __shared__ float sh[4];
  int b = blockIdx.x, i = threadIdx.x;
  bool ok = (i < NPG);
  float ss = ok ? s_state[b*NPG + i] : -1e30f;
  float sr = ok ? s_rel[b*NPG + i]   : -1e30f;
  float m1 = block_max256(ss, sh);
  float e1 = ok ? expf(ss - m1) : 0.f;
  float d1 = block_sum256(e1, sh);
  float m2 = block_max256(sr, sh);
  float e2 = ok ? expf(sr - m2) : 0.f;
  float d2 = block_sum256(e2, sh);
  if (ok){
    float pst = e1/d1, prl = e2/d2;
    float r = psa_s[b*4+3];
    dist[b*NPG + i] = r*prl + (1.f-r)*pst;
    s_rel[b*NPG + i] = 0.f;
  }
}

__global__ __launch_bounds__(256) void final_agg_k(const float* __restrict__ na, const float* __restrict__ dist,
                                                   const float* __restrict__ ps, float* __restrict__ aggregated){
  int b = blockIdx.x, h = threadIdx.x;
  float ps0 = ps[b*4+0], ps1 = ps[b*4+1], ps2 = ps[b*4+2];
  float acc = 0.f;
  for (int i=0;i<NPG;i++){
    int n = b*NPG + i;
    float d = dist[n];
    const float* a = na + (size_t)n*(3*HH);
    acc += d*(ps0*a[h] + ps1*a[HH+h] + ps2*a[2*HH+h]);
  }
  aggregated[b*HH + h] = acc;
}

__global__ void qa_build_k(const float* __restrict__ Q, const float* __restrict__ aggregated,
                           float* __restrict__ QA){
  int idx = blockIdx.x*256 + threadIdx.x;
  if (idx >= BB*2*HH) return;
  int b = idx >> 9, k = idx & 511;
  QA[idx] = (k < HH) ? Q[b*HH + k] : aggregated[b*HH + (k-HH)];
}

// ---------------- host ----------------
extern "C" void kernel_launch(void* const* d_in, const int* in_sizes, int n_in,
                              void* d_out, int out_size, void* d_ws, size_t ws_size,
                              hipStream_t stream) {
  (void)in_sizes; (void)n_in; (void)out_size; (void)ws_size;
  const float* questions     = (const float*)d_in[0];
  const float* node_attrs    = (const float*)d_in[1];
  const float* edge_attrs    = (const float*)d_in[2];
  const float* vocab         = (const float*)d_in[3];
  const float* default_embed = (const float*)d_in[4];
  const float* W_norm        = (const float*)d_in[5];
  const float* lstm_Wih      = (const float*)d_in[6];   // (1024,256) row-major == Bt
  const float* lstm_Whh      = (const float*)d_in[7];   // (1024,256) row-major == Bt
  const float* lstm_bih      = (const float*)d_in[8];
  const float* lstm_bhh      = (const float*)d_in[9];
  const float* rnn_Wih       = (const float*)d_in[10];  // (256,256) row-major == Bt
  const float* rnn_Whh       = (const float*)d_in[11];
  const float* rnn_bih       = (const float*)d_in[12];
  const float* rnn_bhh       = (const float*)d_in[13];
  const float* prop_embeds   = (const float*)d_in[14];
  const float* Ws_property   = (const float*)d_in[15];
  const float* W_state       = (const float*)d_in[16];
  const float* W_relation    = (const float*)d_in[17];
  const float* lin_W         = (const float*)d_in[18];  // (2000,512) row-major == Bt
  const float* lin_b         = (const float*)d_in[19];
  const int*   lengths       = (const int*)d_in[20];
  const int*   edge_src      = (const int*)d_in[23];
  const int*   edge_dst      = (const int*)d_in[24];
  float* out = (float*)d_out;

  char* base = (char*)d_ws;
  size_t off = 0;
  auto alloc = [&](size_t nbytes)->void*{
    void* p = base + off;
    off += (nbytes + 255) & ~(size_t)255;
    return p;
  };

  __hip_bfloat16* qbf     = (__hip_bfloat16*)alloc((size_t)BL*HH*2);
  __hip_bfloat16* WnT_bf  = (__hip_bfloat16*)alloc((size_t)HH*HH*2);
  __hip_bfloat16* xw_bf   = (__hip_bfloat16*)alloc((size_t)BL*HH*2);
  __hip_bfloat16* Cbv     = (__hip_bfloat16*)alloc((size_t)VPAD*HH*2);
  __hip_bfloat16* vT_bf   = (__hip_bfloat16*)alloc((size_t)HH*KPAD*2);
  __hip_bfloat16* Whh_bf  = (__hip_bfloat16*)alloc((size_t)4*HH*HH*2);
  __hip_bfloat16* rWih_bf = (__hip_bfloat16*)alloc((size_t)HH*HH*2);
  __hip_bfloat16* rWhh_bf = (__hip_bfloat16*)alloc((size_t)HH*HH*2);
  __hip_bfloat16* h_bf    = (__hip_bfloat16*)alloc((size_t)BB*HH*2);
  float* e_def    = (float*)alloc((size_t)BL*4);
  float* row_sum  = (float*)alloc((size_t)BL*4);
  float* Vtag     = (float*)alloc((size_t)BL*HH*4);
  float* bsum     = (float*)alloc((size_t)4*HH*4);
  float* h_buf    = (float*)alloc((size_t)BB*HH*4);
  float* Hins     = (float*)alloc((size_t)BB*NSTEPS*HH*4);
  float* R        = (float*)alloc((size_t)BB*NSTEPS*HH*4);
  float* psa      = (float*)alloc((size_t)NSTEPS*BB*4*4);
  float* s_state_all = (float*)alloc((size_t)NSTEPS*NN*4);
  float* acc_e_all   = (float*)alloc((size_t)NSTEPS*EE*4);
  float* s_rel    = (float*)alloc((size_t)NN*4);
  float* dist     = (float*)alloc((size_t)NN*4);
  float* aggregated = (float*)alloc((size_t)BB*HH*4);
  float* QA       = (float*)alloc((size_t)BB*2*HH*4);
  __hip_bfloat16* Pm_bf = (__hip_bfloat16*)alloc((size_t)BL*KPAD*2);
  // Tf region (59MB bf16); gX (16.8MB f32) aliases its start (disjoint in time)
  char*  TfR      = (char*)alloc((size_t)NN*3*HH*2);
  __hip_bfloat16* Tf = (__hip_bfloat16*)TfR;
  float* gX          = (float*)TfR;
  __hip_bfloat16* ET = (__hip_bfloat16*)alloc((size_t)EE*HH*2);

  // ---- setup ----
  init_k<<<(NN+255)/256, 256, 0, stream>>>(dist, s_rel);
  cvt_bf16_k<<<(BL*HH/4+255)/256, 256, 0, stream>>>(questions, qbf, BL*HH);
  tr_cvt_k<<<(HH*HH+255)/256, 256, 0, stream>>>(W_norm, WnT_bf, HH, HH);
  build_cb_k<<<(VPAD*HH+255)/256, 256, 0, stream>>>(vocab, default_embed, Cbv);
  build_vt_k<<<(HH*KPAD+255)/256, 256, 0, stream>>>(vocab, vT_bf);
  cvt_bf16_k<<<(4*HH*HH/4+255)/256, 256, 0, stream>>>(lstm_Whh, Whh_bf, 4*HH*HH);
  cvt_bf16_k<<<(HH*HH/4+255)/256, 256, 0, stream>>>(rnn_Wih, rWih_bf, HH*HH);
  cvt_bf16_k<<<(HH*HH/4+255)/256, 256, 0, stream>>>(rnn_Whh, rWhh_bf, HH*HH);
  bsum_k<<<(4*HH+255)/256, 256, 0, stream>>>(lstm_bih, lstm_bhh, bsum);
  zero_k<<<(BL+255)/256, 256, 0, stream>>>(row_sum, BL);
  zero_k<<<(BL*HH+255)/256, 256, 0, stream>>>(Vtag, BL*HH);

  // ---- phase A: word embedding ----
  mfma_bt_bf16_k<1><<<dim3(2,32,1), 256, 0, stream>>>(qbf, WnT_bf, nullptr, xw_bf,
      HH, HH, HH, HH, HH/32, HH/32, nullptr, nullptr);
  gemm_exp_k<<<dim3(VPAD/128, BL/128, 1), 256, 0, stream>>>(xw_bf, Cbv, Pm_bf, row_sum, e_def);
  inv_k<<<(BL+255)/256, 256, 0, stream>>>(row_sum, BL);
  mfma_bt_bf16_k<2><<<dim3(HH/128, BL/128, 8), 256, 0, stream>>>(
      Pm_bf, vT_bf, Vtag, nullptr, KPAD, KPAD, HH, HH, KPAD/32, 20, nullptr, row_sum);
  vtag_epi_k<<<BL, HH, 0, stream>>>(Vtag, e_def, row_sum, questions);

  // ---- phase B: LSTM encoder ----
  mfma_bt_f32_k<0><<<dim3(8,32,1), 256, 0, stream>>>(Vtag, lstm_Wih, gX, nullptr,
      HH, HH, 4*HH, 4*HH, HH/32, bsum);
  lstm_persist_k<<<16, 1024, 0, stream>>>(gX, Whh_bf, lengths, h_buf, h_bf);

  // ---- phase C: decoder RNN ----
  dec_persist_k<<<16, 1024, 0, stream>>>(h_bf, rWih_bf, rWhh_bf, rnn_bih, rnn_bhh, Hins);

  // ---- phase D: attention -> R; prop_sim for all steps ----
  attention_k<<<BB, 256, 0, stream>>>(Vtag, Hins, lengths, R);
  prop_sim_all_k<<<NSTEPS*BB, 256, 0, stream>>>(R, prop_embeds, psa);

  // ---- phase E: step-invariant heavy GEMMs (bf16 out). Clobbers gX (dead). ----
  for (int p=0; p<3; p++)
    mfma_bt_f32_k<1><<<dim3(2,NN/128,1), 256, 0, stream>>>(
        node_attrs + (size_t)p*HH, Ws_property + (size_t)p*HH*HH,
        nullptr, Tf + (size_t)p*HH, 3*HH, HH, 3*HH, HH, HH/32, nullptr);
  mfma_bt_f32_k<1><<<dim3(2,EE/128,1), 256, 0, stream>>>(
      edge_attrs, Ws_property + (size_t)3*HH*HH,
      nullptr, ET, HH, HH, HH, HH, HH/32, nullptr);

  // ---- phase F: single pass over Tf/ET, then 4 cheap sequential steps ----
  nsm_all_k<<<NN/4 + EE/4, 256, 0, stream>>>(
      Tf, ET, R, psa, W_state, W_relation, s_state_all, acc_e_all);
  for (int s=0; s<NSTEPS; s++){
    rel_scatter_k<<<(EE+255)/256, 256, 0, stream>>>(
        acc_e_all + (size_t)s*EE, dist, edge_src, edge_dst, s_rel);
    nsm_update_k<<<BB, 256, 0, stream>>>(
        s_state_all + (size_t)s*NN, s_rel, psa + (size_t)s*BB*4, dist);
  }

  // ---- phase G: readout ----
  final_agg_k<<<BB, 256, 0, stream>>>(node_attrs, dist, psa + (size_t)3*BB*4, aggregated);
  qa_build_k<<<(BB*2*HH+255)/256, 256, 0, stream>>>(h_buf, aggregated, QA);
  mfma_bt_f32_k<0><<<dim3(16,2,1), 256, 0, stream>>>(QA, lin_W, out, nullptr,
      2*HH, 2*HH, OUTD, OUTD, 2*HH/32, lin_b);
}

// Round 4
// 983.353 us; speedup vs baseline: 1.2654x; 1.0183x over previous
//
#include <hip/hip_runtime.h>
#include <hip/hip_bf16.h>
#include <math.h>

// Problem constants
#define BB 256
#define LL 16
#define HH 256
#define VV 5000
#define NPG 150
#define DEG 4
#define NSTEPS 4
#define OUTD 2000
#define NN (BB*NPG)      // 38400
#define EE (BB*NPG*DEG)  // 153600
#define BL (BB*LL)       // 4096
#define VPAD 5120        // logits column pad (40*128)
#define KPAD 5024        // Pm K pad (157*32)
#define EPG (NPG*DEG)    // 600 edges per graph

// ---------------- helpers ----------------
__device__ __forceinline__ float wred_sum(float v){
  #pragma unroll
  for(int o=32;o;o>>=1) v += __shfl_down(v,o,64);
  return v;
}
__device__ __forceinline__ float wred_max(float v){
  #pragma unroll
  for(int o=32;o;o>>=1) v = fmaxf(v,__shfl_down(v,o,64));
  return v;
}
__device__ __forceinline__ float block_sum256(float v, float* sh){
  v = wred_sum(v);
  __syncthreads();
  if((threadIdx.x&63)==0) sh[threadIdx.x>>6]=v;
  __syncthreads();
  return sh[0]+sh[1]+sh[2]+sh[3];
}
__device__ __forceinline__ float block_max256(float v, float* sh){
  v = wred_max(v);
  __syncthreads();
  if((threadIdx.x&63)==0) sh[threadIdx.x>>6]=v;
  __syncthreads();
  return fmaxf(fmaxf(sh[0],sh[1]),fmaxf(sh[2],sh[3]));
}
__device__ __forceinline__ float eluf(float x){ return x>0.f ? x : expm1f(x); }
__device__ __forceinline__ float sigf(float x){ return 1.f/(1.f+expf(-x)); }
// fast saturating sigmoid/tanh (v_exp + v_rcp; ~1e-7 rel err, exact limits)
__device__ __forceinline__ float fsig(float x){
  return __builtin_amdgcn_rcpf(1.f + __expf(-x));
}
__device__ __forceinline__ float ftanh(float x){
  return 1.f - 2.f*__builtin_amdgcn_rcpf(1.f + __expf(2.f*x));
}
__device__ __forceinline__ float b2f(unsigned short s){
  union{float f; unsigned int u;} x; x.u = ((unsigned int)s)<<16; return x.f;
}
__device__ __forceinline__ unsigned short f2bf_bits(float x){
  union { __hip_bfloat16 h; unsigned short s; } u; u.h = __float2bfloat16(x); return u.s;
}

// async global->LDS 16B (gfx950), lds dest = wave-uniform base + lane*16
__device__ __forceinline__ void async16(void* lds, const void* g){
  __builtin_amdgcn_global_load_lds(
      (const __attribute__((address_space(1))) unsigned int*)g,
      (__attribute__((address_space(3))) unsigned int*)lds, 16, 0, 0);
}

typedef __attribute__((ext_vector_type(8))) short short8;
typedef __attribute__((ext_vector_type(4))) float f32x4;

__device__ __forceinline__ short8 pack8(float4 a, float4 b){
  short8 r;
  r[0]=(short)f2bf_bits(a.x); r[1]=(short)f2bf_bits(a.y);
  r[2]=(short)f2bf_bits(a.z); r[3]=(short)f2bf_bits(a.w);
  r[4]=(short)f2bf_bits(b.x); r[5]=(short)f2bf_bits(b.y);
  r[6]=(short)f2bf_bits(b.z); r[7]=(short)f2bf_bits(b.w);
  return r;
}

// =======================================================================
// MFMA GEMM, C[m,n] = sum_k A[m,k]*Bt[n,k].  128x128 tile, BK=32, 4 waves.
// EPI: 0 = f32 store (+bias, col<Nreal), 1 = bf16 store, 2 = f32 atomicAdd
//      (EPI 2: optional per-row scale rscale[row])
// =======================================================================
template<int EPI>
__global__ __launch_bounds__(256) void mfma_bt_bf16_k(
    const __hip_bfloat16* __restrict__ A, const __hip_bfloat16* __restrict__ Bt,
    float* __restrict__ Cf, __hip_bfloat16* __restrict__ Cb,
    int lda, int ldb, int ldc, int Nreal,
    int kItersTotal, int kPerSplit, const float* __restrict__ bias,
    const float* __restrict__ rscale)
{
  __shared__ __hip_bfloat16 As[128*32];
  __shared__ __hip_bfloat16 Bs[128*32];
  const int bm = blockIdx.y*128, bn = blockIdx.x*128;
  const int tid = threadIdx.x;
  int k0 = blockIdx.z * kPerSplit;
  int k1 = k0 + kPerSplit; if (k1 > kItersTotal) k1 = kItersTotal;
  const int lane = tid & 63, wave = tid >> 6;
  const int quad = lane >> 4, r16 = lane & 15;
  const int wr = wave >> 1, wc = wave & 1;
  f32x4 acc[4][4] = {};
  const int c0 = tid, c1 = tid + 256;
  const int ar0 = c0 >> 2, ak0 = (c0 & 3)*8;
  const int ar1 = c1 >> 2, ak1 = (c1 & 3)*8;
  const __hip_bfloat16* Ab = A + (size_t)bm*lda;
  const __hip_bfloat16* Bb = Bt + (size_t)bn*ldb;
  for (int kk = k0; kk < k1; ++kk){
    const int kb = kk*32;
    async16(&As[c0*8], Ab + (size_t)ar0*lda + kb + ak0);
    async16(&As[c1*8], Ab + (size_t)ar1*lda + kb + ak1);
    async16(&Bs[c0*8], Bb + (size_t)ar0*ldb + kb + ak0);
    async16(&Bs[c1*8], Bb + (size_t)ar1*ldb + kb + ak1);
    __syncthreads();
    short8 av[4], bv[4];
    #pragma unroll
    for (int i=0;i<4;i++){
      av[i] = *(const short8*)&As[(wr*64 + i*16 + r16)*32 + quad*8];
      bv[i] = *(const short8*)&Bs[(wc*64 + i*16 + r16)*32 + quad*8];
    }
    #pragma unroll
    for (int i=0;i<4;i++)
      #pragma unroll
      for (int j=0;j<4;j++)
        acc[i][j] = __builtin_amdgcn_mfma_f32_16x16x32_bf16(av[i], bv[j], acc[i][j], 0,0,0);
    __syncthreads();
  }
  #pragma unroll
  for (int i=0;i<4;i++){
    int row = bm + wr*64 + i*16 + quad*4;
    #pragma unroll
    for (int j=0;j<4;j++){
      int col = bn + wc*64 + j*16 + r16;
      if (col >= Nreal) continue;
      #pragma unroll
      for (int r=0;r<4;r++){
        float v = acc[i][j][r];
        if (EPI==0){ if (bias) v += bias[col]; Cf[(size_t)(row+r)*ldc + col] = v; }
        else if (EPI==1){ Cb[(size_t)(row+r)*ldc + col] = __float2bfloat16(v); }
        else { if (rscale) v *= rscale[row+r]; atomicAdd(&Cf[(size_t)(row+r)*ldc + col], v); }
      }
    }
  }
}

// Same GEMM, f32 global operands, packed bf16 staging (2x float4 -> 1x b128 LDS write)
template<int EPI>
__global__ __launch_bounds__(256) void mfma_bt_f32_k(
    const float* __restrict__ A, const float* __restrict__ Bt,
    float* __restrict__ Cf, __hip_bfloat16* __restrict__ Cb,
    int lda, int ldb, int ldc, int Nreal,
    int kIters, const float* __restrict__ bias)
{
  __shared__ __hip_bfloat16 As[128*32];
  __shared__ __hip_bfloat16 Bs[128*32];
  const int bm = blockIdx.y*128, bn = blockIdx.x*128;
  const int tid = threadIdx.x;
  const int lane = tid & 63, wave = tid >> 6;
  const int quad = lane >> 4, r16 = lane & 15;
  const int wr = wave >> 1, wc = wave & 1;
  f32x4 acc[4][4] = {};
  for (int kk = 0; kk < kIters; ++kk){
    const int kb = kk*32;
    #pragma unroll
    for (int i=0;i<2;i++){
      int c = tid + i*256;
      int row = c >> 2, k0 = (c & 3)*8;
      const float* src = A + (size_t)(bm+row)*lda + kb + k0;
      float4 v0 = *(const float4*)(src);
      float4 v1 = *(const float4*)(src+4);
      *(short8*)&As[row*32 + k0] = pack8(v0, v1);
    }
    #pragma unroll
    for (int i=0;i<2;i++){
      int c = tid + i*256;
      int row = c >> 2, k0 = (c & 3)*8;
      float4 v0 = {0.f,0.f,0.f,0.f}, v1 = {0.f,0.f,0.f,0.f};
      if (bn + row < Nreal){
        const float* src = Bt + (size_t)(bn+row)*ldb + kb + k0;
        v0 = *(const float4*)(src);
        v1 = *(const float4*)(src+4);
      }
      *(short8*)&Bs[row*32 + k0] = pack8(v0, v1);
    }
    __syncthreads();
    short8 av[4], bv[4];
    #pragma unroll
    for (int i=0;i<4;i++){
      av[i] = *(const short8*)&As[(wr*64 + i*16 + r16)*32 + quad*8];
      bv[i] = *(const short8*)&Bs[(wc*64 + i*16 + r16)*32 + quad*8];
    }
    #pragma unroll
    for (int i=0;i<4;i++)
      #pragma unroll
      for (int j=0;j<4;j++)
        acc[i][j] = __builtin_amdgcn_mfma_f32_16x16x32_bf16(av[i], bv[j], acc[i][j], 0,0,0);
    __syncthreads();
  }
  #pragma unroll
  for (int i=0;i<4;i++){
    int row = bm + wr*64 + i*16 + quad*4;
    #pragma unroll
    for (int j=0;j<4;j++){
      int col = bn + wc*64 + j*16 + r16;
      if (col >= Nreal) continue;
      #pragma unroll
      for (int r=0;r<4;r++){
        float v = acc[i][j][r];
        if (EPI==0){ if (bias) v += bias[col]; Cf[(size_t)(row+r)*ldc + col] = v; }
        else { Cb[(size_t)(row+r)*ldc + col] = __float2bfloat16(v); }
      }
    }
  }
}

// Fused logits GEMM + exp epilogue: Pm[r][c] = exp(logit) (unnormalized, bf16),
// row_sum[r] += partial sums (cols 0..VV), e_def[r] = exp(logit[VV]).
__global__ __launch_bounds__(256) void gemm_exp_k(
    const __hip_bfloat16* __restrict__ A, const __hip_bfloat16* __restrict__ Bt,
    __hip_bfloat16* __restrict__ Pm, float* __restrict__ row_sum,
    float* __restrict__ e_def)
{
  __shared__ __hip_bfloat16 As[128*32];
  __shared__ __hip_bfloat16 Bs[128*32];
  const int bm = blockIdx.y*128, bn = blockIdx.x*128;
  const int tid = threadIdx.x;
  const int lane = tid & 63, wave = tid >> 6;
  const int quad = lane >> 4, r16 = lane & 15;
  const int wr = wave >> 1, wc = wave & 1;
  f32x4 acc[4][4] = {};
  const int c0 = tid, c1 = tid + 256;
  const int ar0 = c0 >> 2, ak0 = (c0 & 3)*8;
  const int ar1 = c1 >> 2, ak1 = (c1 & 3)*8;
  const __hip_bfloat16* Ab = A + (size_t)bm*HH;
  const __hip_bfloat16* Bb = Bt + (size_t)bn*HH;
  for (int kk = 0; kk < HH/32; ++kk){
    const int kb = kk*32;
    async16(&As[c0*8], Ab + (size_t)ar0*HH + kb + ak0);
    async16(&As[c1*8], Ab + (size_t)ar1*HH + kb + ak1);
    async16(&Bs[c0*8], Bb + (size_t)ar0*HH + kb + ak0);
    async16(&Bs[c1*8], Bb + (size_t)ar1*HH + kb + ak1);
    __syncthreads();
    short8 av[4], bv[4];
    #pragma unroll
    for (int i=0;i<4;i++){
      av[i] = *(const short8*)&As[(wr*64 + i*16 + r16)*32 + quad*8];
      bv[i] = *(const short8*)&Bs[(wc*64 + i*16 + r16)*32 + quad*8];
    }
    #pragma unroll
    for (int i=0;i<4;i++)
      #pragma unroll
      for (int j=0;j<4;j++)
        acc[i][j] = __builtin_amdgcn_mfma_f32_16x16x32_bf16(av[i], bv[j], acc[i][j], 0,0,0);
    __syncthreads();
  }
  #pragma unroll
  for (int i=0;i<4;i++){
    int rowb = bm + wr*64 + i*16 + quad*4;
    float rsum[4] = {0.f,0.f,0.f,0.f};
    #pragma unroll
    for (int j=0;j<4;j++){
      int col = bn + wc*64 + j*16 + r16;
      #pragma unroll
      for (int r=0;r<4;r++){
        float e = (col <= VV) ? expf(acc[i][j][r]) : 0.f;
        rsum[r] += e;
        if (col < KPAD) Pm[(size_t)(rowb+r)*KPAD + col] = __float2bfloat16(col < VV ? e : 0.f);
        if (col == VV) e_def[rowb+r] = e;
      }
    }
    #pragma unroll
    for (int r=0;r<4;r++){
      float s = rsum[r];
      s += __shfl_xor(s, 1, 64);
      s += __shfl_xor(s, 2, 64);
      s += __shfl_xor(s, 4, 64);
      s += __shfl_xor(s, 8, 64);
      if (r16 == 0) atomicAdd(&row_sum[rowb+r], s);
    }
  }
}

// =======================================================================
// Persistent batch-parallel LSTM, v5: 16 blocks x 1024 threads (16 waves).
// amdgpu_waves_per_eu(4,4) pins the allocator at 4 waves/EU (= exactly our
// 16-wave/1-block-per-CU shape, LDS-forced) -> 128-VGPR budget. v4 compiled
// at 64 VGPR: the 64-VGPR "register weights" were rematerialized into
// per-step global loads. With the pin they stay truly resident.
// Weight placement per wave (4 gate-blocks of 16 rows, K=256 cols):
//   - kc 0..3 (cols 0..127):   registers, ALL waves (16 short8 = 64 VGPR)
//   - kc 4..7 (cols 128..255): LDS Wl for waves 0..7 (512 rows x 132 stride)
//   - kc 4..7 waves 8..15:     streamed from L2 each step (pipelined)
// =======================================================================
__global__ __launch_bounds__(1024)
__attribute__((amdgpu_waves_per_eu(4, 4)))
void lstm_persist_k(
    const float* __restrict__ gX, const __hip_bfloat16* __restrict__ Whh_bf,
    const int* __restrict__ lengths,
    float* __restrict__ h_out, __hip_bfloat16* __restrict__ hbf_out)
{
  __shared__ __hip_bfloat16 Wl[512*132];      // kc4..7, waves 0..7 (135.2KB)
  __shared__ __hip_bfloat16 hbuf[2][16*264];  // double-buffered recurrent h
  const int bg = blockIdx.x, tid = threadIdx.x;
  const int lane = tid & 63, w = tid >> 6;
  const int quad = lane >> 4, r16 = lane & 15;
  const int hb = w*16;
  // preload Wl: row = ww*64 + g*16 + rr  <->  Whh row g*256 + ww*16 + rr, cols 128..255
  for (int idx = tid; idx < 512*16; idx += 1024){
    int row = idx >> 4, c8 = (idx & 15)*8;
    int ww = row >> 6, g = (row >> 4) & 3, rr = row & 15;
    *(short8*)&Wl[row*132 + c8] =
        *(const short8*)&Whh_bf[((size_t)(g*256 + ww*16 + rr))*256 + 128 + c8];
  }
  // register-resident weights: kc 0..3, all waves (64 VGPR)
  short8 rW[4][4];
  #pragma unroll
  for (int kc=0; kc<4; kc++)
    #pragma unroll
    for (int g=0; g<4; g++)
      rW[kc][g] = *(const short8*)&Whh_bf[((size_t)(g*256 + hb + r16))*256 + kc*32 + quad*8];
  for (int i = tid; i < 16*264; i += 1024) hbuf[0][i] = __float2bfloat16(0.f);
  int lenr[4];
  #pragma unroll
  for (int r=0;r<4;r++) lenr[r] = lengths[bg*16 + quad*4 + r];
  __syncthreads();
  f32x4 cstate = {0.f,0.f,0.f,0.f};
  f32x4 hstate = {0.f,0.f,0.f,0.f};
  int p = 0;
  const float* gXb = gX + (size_t)bg*16*LL*(4*HH) + hb + r16;
  for (int t=0; t<LL; t++){
    // gx prefetch (independent of h_{t-1}; in flight across the MFMA phase)
    float gxv[4][4];
    #pragma unroll
    for (int r=0;r<4;r++)
      #pragma unroll
      for (int g=0;g<4;g++)
        gxv[r][g] = gXb[((size_t)((quad*4+r)*LL + t))*(4*HH) + g*HH];
    f32x4 acc[4] = {};
    const __hip_bfloat16* hr = hbuf[p];
    #pragma unroll
    for (int kc=0; kc<4; kc++){
      short8 a = *(const short8*)&hr[r16*264 + kc*32 + quad*8];
      #pragma unroll
      for (int g=0; g<4; g++)
        acc[g] = __builtin_amdgcn_mfma_f32_16x16x32_bf16(a, rW[kc][g], acc[g], 0,0,0);
    }
    if (w < 8){
      #pragma unroll
      for (int kc=4; kc<8; kc++){
        short8 a = *(const short8*)&hr[r16*264 + kc*32 + quad*8];
        #pragma unroll
        for (int g=0; g<4; g++){
          short8 b = *(const short8*)&Wl[(w*64 + g*16 + r16)*132 + (kc-4)*32 + quad*8];
          acc[g] = __builtin_amdgcn_mfma_f32_16x16x32_bf16(a, b, acc[g], 0,0,0);
        }
      }
    } else {
      #pragma unroll
      for (int kc=4; kc<8; kc++){
        short8 a = *(const short8*)&hr[r16*264 + kc*32 + quad*8];
        #pragma unroll
        for (int g=0; g<4; g++){
          short8 b = *(const short8*)&Whh_bf[((size_t)(g*256 + hb + r16))*256 + kc*32 + quad*8];
          acc[g] = __builtin_amdgcn_mfma_f32_16x16x32_bf16(a, b, acc[g], 0,0,0);
        }
      }
    }
    #pragma unroll
    for (int r=0;r<4;r++){
      int batch = quad*4 + r;
      float gi = acc[0][r] + gxv[r][0];
      float gf = acc[1][r] + gxv[r][1];
      float gc = acc[2][r] + gxv[r][2];
      float go = acc[3][r] + gxv[r][3];
      float cn = fsig(gf)*cstate[r] + fsig(gi)*ftanh(gc);
      float hn = fsig(go)*ftanh(cn);
      if (t < lenr[r]){ cstate[r] = cn; hstate[r] = hn; }
      hbuf[p^1][batch*264 + hb + r16] = __float2bfloat16(hstate[r]);
    }
    p ^= 1;
    __syncthreads();
  }
  #pragma unroll
  for (int r=0;r<4;r++){
    int batch = quad*4 + r;
    size_t o = (size_t)(bg*16+batch)*HH + hb + r16;
    h_out[o] = hstate[r];
    hbf_out[o] = __float2bfloat16(hstate[r]);
  }
}

// Persistent batch-parallel decoder RNN: 16 blocks x 1024 threads.
// Entire Whh (128KB) cached in LDS; qp and x-state in registers; step 0 has
// h=0 so its MFMA is skipped entirely. waves_per_eu(4,4) -> 128 VGPR.
__global__ __launch_bounds__(1024)
__attribute__((amdgpu_waves_per_eu(4, 4)))
void dec_persist_k(
    const __hip_bfloat16* __restrict__ Qbf, const __hip_bfloat16* __restrict__ Wih_bf,
    const __hip_bfloat16* __restrict__ Whh_bf,
    const float* __restrict__ bih, const float* __restrict__ bhh,
    float* __restrict__ Hins)
{
  __shared__ __hip_bfloat16 Wl[256*264];     // full Whh, 132KB
  __shared__ __hip_bfloat16 xb[2][16*264];
  const int bg = blockIdx.x, tid = threadIdx.x;
  const int lane = tid & 63, w = tid >> 6;
  const int quad = lane >> 4, r16 = lane & 15;
  const int col = w*16 + r16;
  for (int c = tid; c < 8192; c += 1024){
    int row = c >> 5, ci = (c & 31)*8;
    *(short8*)&Wl[row*264 + ci] = *(const short8*)&Whh_bf[(size_t)row*256 + ci];
  }
  // qp = Q @ Wih^T  (A rows straight from global; Wih streamed from L2 once)
  f32x4 qp = {};
  #pragma unroll
  for (int kc=0; kc<8; kc++){
    short8 a = *(const short8*)&Qbf[(size_t)(bg*16 + r16)*HH + kc*32 + quad*8];
    short8 b = *(const short8*)&Wih_bf[(size_t)col*HH + kc*32 + quad*8];
    qp = __builtin_amdgcn_mfma_f32_16x16x32_bf16(a, b, qp, 0,0,0);
  }
  const float bihv = bih[col], bhhv = bhh[col];
  __syncthreads();           // Wl ready
  // s = 0: hx=0 -> x = relu(qp + bih + bhh)
  #pragma unroll
  for (int r=0;r<4;r++){
    int batch = quad*4 + r;
    float v = fmaxf(qp[r] + bihv + bhhv, 0.f);
    xb[0][batch*264 + col] = __float2bfloat16(v);
    Hins[(size_t)(bg*16+batch)*(NSTEPS*HH) + 0*HH + col] = v;
  }
  __syncthreads();
  int p = 0;
  for (int s=1; s<NSTEPS; s++){
    f32x4 acc = {};
    #pragma unroll
    for (int kc=0; kc<8; kc++){
      short8 a = *(const short8*)&xb[p][r16*264 + kc*32 + quad*8];
      short8 b = *(const short8*)&Wl[col*264 + kc*32 + quad*8];
      acc = __builtin_amdgcn_mfma_f32_16x16x32_bf16(a, b, acc, 0,0,0);
    }
    #pragma unroll
    for (int r=0;r<4;r++){
      int batch = quad*4 + r;
      float v = fmaxf(qp[r] + bihv + acc[r] + bhhv, 0.f);
      xb[p^1][batch*264 + col] = __float2bfloat16(v);
      Hins[(size_t)(bg*16+batch)*(NSTEPS*HH) + s*HH + col] = v;
    }
    p ^= 1;
    __syncthreads();
  }
}

// ---------------- small utility kernels ----------------
__global__ void cvt_bf16_k(const float* __restrict__ src, __hip_bfloat16* __restrict__ dst, int n){
  int i = (blockIdx.x*256 + threadIdx.x)*4;
  if (i >= n) return;
  float4 v = *(const float4*)(src + i);
  dst[i]   = __float2bfloat16(v.x);
  dst[i+1] = __float2bfloat16(v.y);
  dst[i+2] = __float2bfloat16(v.z);
  dst[i+3] = __float2bfloat16(v.w);
}

__global__ void tr_cvt_k(const float* __restrict__ src, __hip_bfloat16* __restrict__ dst, int R, int Ccols){
  int idx = blockIdx.x*256 + threadIdx.x;
  if (idx >= R*Ccols) return;
  int r = idx / Ccols, c = idx % Ccols;
  dst[(size_t)c*R + r] = __float2bfloat16(src[idx]);
}

__global__ void build_cb_k(const float* __restrict__ vocab, const float* __restrict__ de,
                           __hip_bfloat16* __restrict__ Cb){
  int idx = blockIdx.x*256 + threadIdx.x;
  if (idx >= VPAD*HH) return;
  int v = idx >> 8, h = idx & 255;
  float x = (v < VV) ? vocab[(size_t)v*HH + h] : (v == VV ? de[h] : 0.f);
  Cb[idx] = __float2bfloat16(x);
}

__global__ void build_vt_k(const float* __restrict__ vocab, __hip_bfloat16* __restrict__ VT){
  int idx = blockIdx.x*256 + threadIdx.x;
  if (idx >= HH*KPAD) return;
  int h = idx / KPAD, v = idx % KPAD;
  VT[idx] = __float2bfloat16(v < VV ? vocab[(size_t)v*HH + h] : 0.f);
}

__global__ void bsum_k(const float* a, const float* b, float* o){
  int i = blockIdx.x*256 + threadIdx.x;
  if (i < 4*HH) o[i] = a[i] + b[i];
}

__global__ void zero_k(float* p, int n){
  int idx = blockIdx.x*256 + threadIdx.x;
  if (idx < n) p[idx] = 0.f;
}

__global__ void inv_k(float* p, int n){
  int idx = blockIdx.x*256 + threadIdx.x;
  if (idx < n) p[idx] = 1.f/p[idx];
}

__global__ void vtag_epi_k(float* __restrict__ Vtag, const float* __restrict__ e_def,
                           const float* __restrict__ inv_s, const float* __restrict__ words){
  int r = blockIdx.x, h = threadIdx.x;
  size_t o = (size_t)r*HH + h;
  Vtag[o] += e_def[r]*inv_s[r]*words[o];
}

// attention per graph
__global__ __launch_bounds__(256) void attention_k(const float* __restrict__ Vtag,
                                                   const float* __restrict__ Hins,
                                                   const int* __restrict__ lengths,
                                                   float* __restrict__ R){
  __shared__ float Vl[LL][HH];
  __shared__ float Hn[NSTEPS][HH];
  __shared__ float att[NSTEPS][LL];
  int b = blockIdx.x, tid = threadIdx.x;
  for (int idx=tid; idx<LL*HH; idx+=256){ int l=idx>>8, h=idx&255; Vl[l][h] = Vtag[((size_t)b*LL+l)*HH + h]; }
  for (int idx=tid; idx<NSTEPS*HH; idx+=256){ Hn[idx>>8][idx&255] = Hins[(size_t)b*(NSTEPS*HH) + idx]; }
  __syncthreads();
  if (tid < NSTEPS*LL){
    int n2 = tid>>4, l = tid&15;
    float s = 0.f;
    for (int k=0;k<HH;k++) s += Hn[n2][k]*Vl[l][k];
    att[n2][l] = s;
  }
  __syncthreads();
  int len = lengths[b];
  if (tid < NSTEPS){
    float m = -1e30f;
    for (int l=0;l<len;l++) m = fmaxf(m, att[tid][l]);
    float s = 0.f;
    for (int l=0;l<LL;l++){ float e = (l<len)? expf(att[tid][l]-m) : 0.f; att[tid][l]=e; s+=e; }
    float inv = 1.f/s;
    for (int l=0;l<LL;l++) att[tid][l] *= inv;
  }
  __syncthreads();
  {
    int n2 = tid>>6, h0 = (tid&63)*4;
    float r0=0,r1=0,r2=0,r3=0;
    for (int l=0;l<LL;l++){
      float w = att[n2][l];
      r0 += w*Vl[l][h0]; r1 += w*Vl[l][h0+1]; r2 += w*Vl[l][h0+2]; r3 += w*Vl[l][h0+3];
    }
    float* o = R + (size_t)b*(NSTEPS*HH) + n2*HH + h0;
    o[0]=r0; o[1]=r1; o[2]=r2; o[3]=r3;
  }
}

// prop_sim for ALL steps: psa[s][b][4]
__global__ __launch_bounds__(256) void prop_sim_all_k(const float* __restrict__ R,
                                                      const float* __restrict__ pe,
                                                      float* __restrict__ psa){
  __shared__ float sp[4];
  int gb = blockIdx.x;
  int s = gb >> 8, b = gb & 255;
  int tid = threadIdx.x;
  int p = tid>>6, lane = tid&63;
  const float* instr = R + (size_t)b*(NSTEPS*HH) + s*HH;
  float v = 0.f;
  for (int h=lane; h<HH; h+=64) v += instr[h]*pe[p*HH+h];
  v = wred_sum(v);
  if (lane==0) sp[p] = v;
  __syncthreads();
  if (tid==0){
    float m = fmaxf(fmaxf(sp[0],sp[1]),fmaxf(sp[2],sp[3]));
    float e0=expf(sp[0]-m), e1=expf(sp[1]-m), e2=expf(sp[2]-m), e3=expf(sp[3]-m);
    float ss = e0+e1+e2+e3;
    float* o = psa + (size_t)s*BB*4 + b*4;
    o[0]=e0/ss; o[1]=e1/ss; o[2]=e2/ss; o[3]=e3/ss;
  }
}

// ONE pass over Tf/ET computing ALL 4 steps' reductions (node scores and
// edge scalars). Step-dependence enters only through instr/psa, NOT dist,
// so the 137MB of Tf+ET is read once instead of 4x.
__global__ __launch_bounds__(256) void nsm_all_k(
    const __hip_bfloat16* __restrict__ Tf, const __hip_bfloat16* __restrict__ ET,
    const float* __restrict__ R, const float* __restrict__ psa,
    const float* __restrict__ W_state, const float* __restrict__ Wr,
    float* __restrict__ s_state_all, float* __restrict__ acc_e_all)
{
  const int wave = threadIdx.x >> 6, lane = threadIdx.x & 63;
  const int h0 = lane*4;
  if (blockIdx.x < NN/4){
    int n = blockIdx.x*4 + wave;
    int g = n / NPG;
    const unsigned short* t = (const unsigned short*)(Tf + (size_t)n*(3*HH));
    ushort4 t0 = *(const ushort4*)(t + h0);
    ushort4 t1 = *(const ushort4*)(t + HH + h0);
    ushort4 t2 = *(const ushort4*)(t + 2*HH + h0);
    float4 wv = *(const float4*)(W_state + h0);
    #pragma unroll
    for (int s=0; s<NSTEPS; s++){
      const float* instr = R + (size_t)g*(NSTEPS*HH) + s*HH;
      const float* ps = psa + (size_t)s*BB*4 + g*4;
      float ps0 = ps[0], ps1 = ps[1], ps2 = ps[2];
      float4 iv = *(const float4*)(instr + h0);
      float acc;
      acc  = eluf(iv.x*(ps0*b2f(t0.x)+ps1*b2f(t1.x)+ps2*b2f(t2.x)))*wv.x;
      acc += eluf(iv.y*(ps0*b2f(t0.y)+ps1*b2f(t1.y)+ps2*b2f(t2.y)))*wv.y;
      acc += eluf(iv.z*(ps0*b2f(t0.z)+ps1*b2f(t1.z)+ps2*b2f(t2.z)))*wv.z;
      acc += eluf(iv.w*(ps0*b2f(t0.w)+ps1*b2f(t1.w)+ps2*b2f(t2.w)))*wv.w;
      acc = wred_sum(acc);
      if (lane==0) s_state_all[(size_t)s*NN + n] = acc;
    }
  } else {
    int e = (blockIdx.x - NN/4)*4 + wave;
    int b = e / (NPG*DEG);
    const unsigned short* et = (const unsigned short*)(ET + (size_t)e*HH);
    ushort4 ev = *(const ushort4*)(et + h0);
    float4 wv = *(const float4*)(Wr + h0);
    #pragma unroll
    for (int s=0; s<NSTEPS; s++){
      const float* instr = R + (size_t)b*(NSTEPS*HH) + s*HH;
      float4 iv = *(const float4*)(instr + h0);
      float acc;
      acc  = eluf(iv.x*b2f(ev.x))*wv.x;
      acc += eluf(iv.y*b2f(ev.y))*wv.y;
      acc += eluf(iv.z*b2f(ev.z))*wv.z;
      acc += eluf(iv.w*b2f(ev.w))*wv.w;
      acc = wred_sum(acc);
      if (lane==0) acc_e_all[(size_t)s*EE + e] = acc;
    }
  }
}

// All 4 NSM steps fused, one block per graph: edges never cross graphs
// (esrc/edst = rand(0,NPG) + b*NPG), so scatter + both segment softmaxes +
// dist update run entirely in LDS. Replaces 8 tiny dependent launches.
__global__ __launch_bounds__(256) void nsm_steps_k(
    const float* __restrict__ s_state_all, const float* __restrict__ acc_e_all,
    const int* __restrict__ esrc, const int* __restrict__ edst,
    const float* __restrict__ psa, float* __restrict__ dist_out)
{
  __shared__ float nd[NPG];       // running dist
  __shared__ float srel[NPG];
  __shared__ float sh[4];
  __shared__ short les[EPG], led[EPG];
  const int b = blockIdx.x, tid = threadIdx.x;
  const int base_e = b*EPG, base_n = b*NPG;
  for (int j = tid; j < EPG; j += 256){
    les[j] = (short)(esrc[base_e + j] - base_n);
    led[j] = (short)(edst[base_e + j] - base_n);
  }
  if (tid < NPG){ nd[tid] = 1.f/(float)NPG; srel[tid] = 0.f; }
  __syncthreads();
  for (int s=0; s<NSTEPS; s++){
    // scatter: srel[dst] += nd[src] * acc_e
    for (int j = tid; j < EPG; j += 256){
      float v = nd[les[j]] * acc_e_all[(size_t)s*EE + base_e + j];
      atomicAdd(&srel[led[j]], v);
    }
    __syncthreads();
    bool ok = (tid < NPG);
    float ss = ok ? s_state_all[(size_t)s*NN + base_n + tid] : -1e30f;
    float sr = ok ? srel[tid] : -1e30f;
    float m1 = block_max256(ss, sh);
    float e1 = ok ? expf(ss - m1) : 0.f;
    float d1 = block_sum256(e1, sh);
    float m2 = block_max256(sr, sh);
    float e2 = ok ? expf(sr - m2) : 0.f;
    float d2 = block_sum256(e2, sh);
    __syncthreads();
    if (ok){
      float r = psa[(size_t)s*BB*4 + b*4 + 3];
      nd[tid] = r*(e2/d2) + (1.f-r)*(e1/d1);
      srel[tid] = 0.f;
    }
    __syncthreads();
  }
  if (tid < NPG) dist_out[base_n + tid] = nd[tid];
}

__global__ __launch_bounds__(256) void final_agg_k(const float* __restrict__ na, const float* __restrict__ dist,
                                                   const float* __restrict__ ps, float* __restrict__ aggregated){
  int b = blockIdx.x, h = threadIdx.x;
  float ps0 = ps[b*4+0], ps1 = ps[b*4+1], ps2 = ps[b*4+2];
  float acc = 0.f;
  for (int i=0;i<NPG;i++){
    int n = b*NPG + i;
    float d = dist[n];
    const float* a = na + (size_t)n*(3*HH);
    acc += d*(ps0*a[h] + ps1*a[HH+h] + ps2*a[2*HH+h]);
  }
  aggregated[b*HH + h] = acc;
}

__global__ void qa_build_k(const float* __restrict__ Q, const float* __restrict__ aggregated,
                           float* __restrict__ QA){
  int idx = blockIdx.x*256 + threadIdx.x;
  if (idx >= BB*2*HH) return;
  int b = idx >> 9, k = idx & 511;
  QA[idx] = (k < HH) ? Q[b*HH + k] : aggregated[b*HH + (k-HH)];
}

// ---------------- host ----------------
extern "C" void kernel_launch(void* const* d_in, const int* in_sizes, int n_in,
                              void* d_out, int out_size, void* d_ws, size_t ws_size,
                              hipStream_t stream) {
  (void)in_sizes; (void)n_in; (void)out_size; (void)ws_size;
  const float* questions     = (const float*)d_in[0];
  const float* node_attrs    = (const float*)d_in[1];
  const float* edge_attrs    = (const float*)d_in[2];
  const float* vocab         = (const float*)d_in[3];
  const float* default_embed = (const float*)d_in[4];
  const float* W_norm        = (const float*)d_in[5];
  const float* lstm_Wih      = (const float*)d_in[6];   // (1024,256) row-major == Bt
  const float* lstm_Whh      = (const float*)d_in[7];   // (1024,256) row-major == Bt
  const float* lstm_bih      = (const float*)d_in[8];
  const float* lstm_bhh      = (const float*)d_in[9];
  const float* rnn_Wih       = (const float*)d_in[10];  // (256,256) row-major == Bt
  const float* rnn_Whh       = (const float*)d_in[11];
  const float* rnn_bih       = (const float*)d_in[12];
  const float* rnn_bhh       = (const float*)d_in[13];
  const float* prop_embeds   = (const float*)d_in[14];
  const float* Ws_property   = (const float*)d_in[15];
  const float* W_state       = (const float*)d_in[16];
  const float* W_relation    = (const float*)d_in[17];
  const float* lin_W         = (const float*)d_in[18];  // (2000,512) row-major == Bt
  const float* lin_b         = (const float*)d_in[19];
  const int*   lengths       = (const int*)d_in[20];
  const int*   edge_src      = (const int*)d_in[23];
  const int*   edge_dst      = (const int*)d_in[24];
  float* out = (float*)d_out;

  char* base = (char*)d_ws;
  size_t off = 0;
  auto alloc = [&](size_t nbytes)->void*{
    void* p = base + off;
    off += (nbytes + 255) & ~(size_t)255;
    return p;
  };

  __hip_bfloat16* qbf     = (__hip_bfloat16*)alloc((size_t)BL*HH*2);
  __hip_bfloat16* WnT_bf  = (__hip_bfloat16*)alloc((size_t)HH*HH*2);
  __hip_bfloat16* xw_bf   = (__hip_bfloat16*)alloc((size_t)BL*HH*2);
  __hip_bfloat16* Cbv     = (__hip_bfloat16*)alloc((size_t)VPAD*HH*2);
  __hip_bfloat16* vT_bf   = (__hip_bfloat16*)alloc((size_t)HH*KPAD*2);
  __hip_bfloat16* Whh_bf  = (__hip_bfloat16*)alloc((size_t)4*HH*HH*2);
  __hip_bfloat16* rWih_bf = (__hip_bfloat16*)alloc((size_t)HH*HH*2);
  __hip_bfloat16* rWhh_bf = (__hip_bfloat16*)alloc((size_t)HH*HH*2);
  __hip_bfloat16* h_bf    = (__hip_bfloat16*)alloc((size_t)BB*HH*2);
  float* e_def    = (float*)alloc((size_t)BL*4);
  float* row_sum  = (float*)alloc((size_t)BL*4);
  float* Vtag     = (float*)alloc((size_t)BL*HH*4);
  float* bsum     = (float*)alloc((size_t)4*HH*4);
  float* h_buf    = (float*)alloc((size_t)BB*HH*4);
  float* Hins     = (float*)alloc((size_t)BB*NSTEPS*HH*4);
  float* R        = (float*)alloc((size_t)BB*NSTEPS*HH*4);
  float* psa      = (float*)alloc((size_t)NSTEPS*BB*4*4);
  float* s_state_all = (float*)alloc((size_t)NSTEPS*NN*4);
  float* acc_e_all   = (float*)alloc((size_t)NSTEPS*EE*4);
  float* dist     = (float*)alloc((size_t)NN*4);
  float* aggregated = (float*)alloc((size_t)BB*HH*4);
  float* QA       = (float*)alloc((size_t)BB*2*HH*4);
  __hip_bfloat16* Pm_bf = (__hip_bfloat16*)alloc((size_t)BL*KPAD*2);
  // Tf region (59MB bf16); gX (16.8MB f32) aliases its start (disjoint in time)
  char*  TfR      = (char*)alloc((size_t)NN*3*HH*2);
  __hip_bfloat16* Tf = (__hip_bfloat16*)TfR;
  float* gX          = (float*)TfR;
  __hip_bfloat16* ET = (__hip_bfloat16*)alloc((size_t)EE*HH*2);

  // ---- setup ----
  cvt_bf16_k<<<(BL*HH/4+255)/256, 256, 0, stream>>>(questions, qbf, BL*HH);
  tr_cvt_k<<<(HH*HH+255)/256, 256, 0, stream>>>(W_norm, WnT_bf, HH, HH);
  build_cb_k<<<(VPAD*HH+255)/256, 256, 0, stream>>>(vocab, default_embed, Cbv);
  build_vt_k<<<(HH*KPAD+255)/256, 256, 0, stream>>>(vocab, vT_bf);
  cvt_bf16_k<<<(4*HH*HH/4+255)/256, 256, 0, stream>>>(lstm_Whh, Whh_bf, 4*HH*HH);
  cvt_bf16_k<<<(HH*HH/4+255)/256, 256, 0, stream>>>(rnn_Wih, rWih_bf, HH*HH);
  cvt_bf16_k<<<(HH*HH/4+255)/256, 256, 0, stream>>>(rnn_Whh, rWhh_bf, HH*HH);
  bsum_k<<<(4*HH+255)/256, 256, 0, stream>>>(lstm_bih, lstm_bhh, bsum);
  zero_k<<<(BL+255)/256, 256, 0, stream>>>(row_sum, BL);
  zero_k<<<(BL*HH+255)/256, 256, 0, stream>>>(Vtag, BL*HH);

  // ---- phase A: word embedding ----
  mfma_bt_bf16_k<1><<<dim3(2,32,1), 256, 0, stream>>>(qbf, WnT_bf, nullptr, xw_bf,
      HH, HH, HH, HH, HH/32, HH/32, nullptr, nullptr);
  gemm_exp_k<<<dim3(VPAD/128, BL/128, 1), 256, 0, stream>>>(xw_bf, Cbv, Pm_bf, row_sum, e_def);
  inv_k<<<(BL+255)/256, 256, 0, stream>>>(row_sum, BL);
  mfma_bt_bf16_k<2><<<dim3(HH/128, BL/128, 8), 256, 0, stream>>>(
      Pm_bf, vT_bf, Vtag, nullptr, KPAD, KPAD, HH, HH, KPAD/32, 20, nullptr, row_sum);
  vtag_epi_k<<<BL, HH, 0, stream>>>(Vtag, e_def, row_sum, questions);

  // ---- phase B: LSTM encoder ----
  mfma_bt_f32_k<0><<<dim3(8,32,1), 256, 0, stream>>>(Vtag, lstm_Wih, gX, nullptr,
      HH, HH, 4*HH, 4*HH, HH/32, bsum);
  lstm_persist_k<<<16, 1024, 0, stream>>>(gX, Whh_bf, lengths, h_buf, h_bf);

  // ---- phase C: decoder RNN ----
  dec_persist_k<<<16, 1024, 0, stream>>>(h_bf, rWih_bf, rWhh_bf, rnn_bih, rnn_bhh, Hins);

  // ---- phase D: attention -> R; prop_sim for all steps ----
  attention_k<<<BB, 256, 0, stream>>>(Vtag, Hins, lengths, R);
  prop_sim_all_k<<<NSTEPS*BB, 256, 0, stream>>>(R, prop_embeds, psa);

  // ---- phase E: step-invariant heavy GEMMs (bf16 out). Clobbers gX (dead). ----
  for (int p=0; p<3; p++)
    mfma_bt_f32_k<1><<<dim3(2,NN/128,1), 256, 0, stream>>>(
        node_attrs + (size_t)p*HH, Ws_property + (size_t)p*HH*HH,
        nullptr, Tf + (size_t)p*HH, 3*HH, HH, 3*HH, HH, HH/32, nullptr);
  mfma_bt_f32_k<1><<<dim3(2,EE/128,1), 256, 0, stream>>>(
      edge_attrs, Ws_property + (size_t)3*HH*HH,
      nullptr, ET, HH, HH, HH, HH, HH/32, nullptr);

  // ---- phase F: one pass over Tf/ET, then all 4 steps fused in one kernel ----
  nsm_all_k<<<NN/4 + EE/4, 256, 0, stream>>>(
      Tf, ET, R, psa, W_state, W_relation, s_state_all, acc_e_all);
  nsm_steps_k<<<BB, 256, 0, stream>>>(
      s_state_all, acc_e_all, edge_src, edge_dst, psa, dist);

  // ---- phase G: readout ----
  final_agg_k<<<BB, 256, 0, stream>>>(node_attrs, dist, psa + (size_t)3*BB*4, aggregated);
  qa_build_k<<<(BB*2*HH+255)/256, 256, 0, stream>>>(h_buf, aggregated, QA);
  mfma_bt_f32_k<0><<<dim3(16,2,1), 256, 0, stream>>>(QA, lin_W, out, nullptr,
      2*HH, 2*HH, OUTD, OUTD, 2*HH/32, lin_b);
}